// Round 1
// baseline (761.276 us; speedup 1.0000x reference)
//
#include <hip/hip_runtime.h>
#include <math.h>

#define D_    1024
#define H_    16
#define DH_   64
#define DC_   256
#define HID_  2048
#define E_    8
#define B_    2
#define T_    2048
#define S_    4096
#define EPS_  1e-6f
#define QKVW_ 3072   // fused qkv row width

typedef unsigned short u16;
typedef short bf16x8 __attribute__((ext_vector_type(8)));
typedef float f32x4 __attribute__((ext_vector_type(4)));

__device__ __forceinline__ float b2f(u16 u) {
    return __uint_as_float(((unsigned int)u) << 16);
}
__device__ __forceinline__ u16 f2b(float f) {
    unsigned int u = __float_as_uint(f);
    u += 0x7FFF + ((u >> 16) & 1);
    return (u16)(u >> 16);
}
__device__ __forceinline__ void g2l16(const u16* g, u16* l) {
    __builtin_amdgcn_global_load_lds(
        (const __attribute__((address_space(1))) void*)g,
        (__attribute__((address_space(3))) void*)l, 16, 0, 0);
}

// ---------------------------------------------------------------------------
// Transpose + fp32->bf16: in (K,N) fp32 -> out (N,K) bf16.
// perm=1: swiglu column interleave for fused epilogue.
// ---------------------------------------------------------------------------
__global__ __launch_bounds__(256) void conv_t(const float* __restrict__ in,
                                              u16* __restrict__ out,
                                              int K, int N,
                                              long inZ, long outZ, int perm) {
    in  += (long)blockIdx.z * inZ;
    out += (long)blockIdx.z * outZ;
    __shared__ float t[32][33];
    const int n0 = blockIdx.x * 32, k0 = blockIdx.y * 32;
    int src_n0 = n0;
    if (perm) {
        int t64 = n0 >> 6;
        src_n0 = ((n0 & 63) == 0) ? t64 * 32 : (N / 2 + t64 * 32);
    }
    const int tx = threadIdx.x & 31, ty = threadIdx.x >> 5;
#pragma unroll
    for (int i = 0; i < 4; i++)
        t[ty + 8 * i][tx] = in[(long)(k0 + ty + 8 * i) * N + src_n0 + tx];
    __syncthreads();
#pragma unroll
    for (int i = 0; i < 4; i++)
        out[(long)(n0 + ty + 8 * i) * K + k0 + tx] = f2b(t[tx][ty + 8 * i]);
}

// bf16 transpose V rows of fused qkv (stride QKVW_) per-head -> Vt [bh][64][T]
__global__ __launch_bounds__(256) void vt_conv(const u16* __restrict__ qkv,
                                               u16* __restrict__ vt) {
    __shared__ u16 t[32][34];
    const int bh = blockIdx.z;
    const int b = bh >> 4, h = bh & 15;
    const int t0 = blockIdx.x * 32, d0 = blockIdx.y * 32;
    const int tx = threadIdx.x & 31, ty = threadIdx.x >> 5;
#pragma unroll
    for (int i = 0; i < 4; i++)
        t[ty + 8 * i][tx] =
            qkv[((long)b * T_ + t0 + ty + 8 * i) * QKVW_ + 2048 + h * 64 + d0 + tx];
    __syncthreads();
#pragma unroll
    for (int i = 0; i < 4; i++)
        vt[((long)bh * 64 + d0 + ty + 8 * i) * T_ + t0 + tx] = t[tx][ty + 8 * i];
}

// Elementwise fp32 -> bf16
__global__ __launch_bounds__(256) void convert_bf16(const float* __restrict__ in,
                                                    u16* __restrict__ out, int n4) {
    int i = blockIdx.x * 256 + threadIdx.x;
    if (i >= n4) return;
    float4 f = ((const float4*)in)[i];
    ushort4 o;
    o.x = f2b(f.x); o.y = f2b(f.y); o.z = f2b(f.z); o.w = f2b(f.w);
    ((ushort4*)out)[i] = o;
}

// ---------------------------------------------------------------------------
// bf16 MFMA GEMM: C(M,N) = A(M,K) @ Bt(N,K)^T. 128x128, BK=32, 4 waves.
// OUTMODE 1: bf16 store | 2: bf16 transposed store (ldo=M)
// OUTMODE 3: swiglu epilogue, dual output: blockIdx.x>=32 -> Cp + S_*HID_
// OUTMODE 5: split-K (gridDim.z=2), fp32 plain store; z=0 -> Cp, z=1 -> Cp2
// ---------------------------------------------------------------------------
template<int OUTMODE>
__global__ __launch_bounds__(256) void gemm_bf16(const u16* __restrict__ A,
                                                 const u16* __restrict__ Bt,
                                                 void* __restrict__ Cp,
                                                 int N, int K, int ldo,
                                                 void* __restrict__ Cp2) {
    __shared__ u16 As[128 * 32];
    __shared__ u16 Bs[128 * 32];
    const int tid  = threadIdx.x;
    const int lane = tid & 63;
    const int wv   = tid >> 6;
    const int wm   = wv >> 1, wn = wv & 1;
    const long row0 = (long)blockIdx.y * 128;
    const long col0 = (long)blockIdx.x * 128;
    const int Klocal = K / gridDim.z;
    const long koff  = (long)blockIdx.z * Klocal;

    f32x4 acc[4][4];
#pragma unroll
    for (int i = 0; i < 4; i++)
#pragma unroll
        for (int j = 0; j < 4; j++) acc[i][j] = (f32x4){0.f, 0.f, 0.f, 0.f};

    const int sr = tid >> 2;
    const int sc = (tid & 3) << 3;
    const u16* Ag  = A  + (row0 + sr) * (long)K + koff + sc;
    const u16* Ag2 = Ag + 64 * (long)K;
    const u16* Bg  = Bt + (col0 + sr) * (long)K + koff + sc;
    const u16* Bg2 = Bg + 64 * (long)K;
    u16* lA  = As + tid * 8;
    u16* lA2 = As + 2048 + tid * 8;
    u16* lB  = Bs + tid * 8;
    u16* lB2 = Bs + 2048 + tid * 8;

    const int fl = lane & 15;
    const int fk = (lane >> 4) << 3;
    const u16* ArA = As + (wm * 64 + fl) * 32 + fk;
    const u16* BrB = Bs + (wn * 64 + fl) * 32 + fk;

    for (int k0 = 0; k0 < Klocal; k0 += 32) {
        __syncthreads();
        g2l16(Ag + k0, lA);
        g2l16(Ag2 + k0, lA2);
        g2l16(Bg + k0, lB);
        g2l16(Bg2 + k0, lB2);
        __syncthreads();
        bf16x8 af[4], bfr[4];
#pragma unroll
        for (int mi = 0; mi < 4; mi++) af[mi]  = *(const bf16x8*)(ArA + mi * 512);
#pragma unroll
        for (int ni = 0; ni < 4; ni++) bfr[ni] = *(const bf16x8*)(BrB + ni * 512);
#pragma unroll
        for (int mi = 0; mi < 4; mi++)
#pragma unroll
            for (int ni = 0; ni < 4; ni++)
                acc[mi][ni] = __builtin_amdgcn_mfma_f32_16x16x32_bf16(
                    af[mi], bfr[ni], acc[mi][ni], 0, 0, 0);
    }

    const int cr = (lane >> 4) << 2;
    const int cc = lane & 15;
#pragma unroll
    for (int mi = 0; mi < 4; mi++) {
#pragma unroll
        for (int r = 0; r < 4; r++) {
            long grow = row0 + wm * 64 + mi * 16 + cr + r;
            if (OUTMODE == 3) {
                u16* outb = (u16*)Cp + (long)(blockIdx.x >> 5) * S_ * HID_;
                u16* hrow = outb + grow * ldo + (blockIdx.x & 31) * 64 + wn * 32;
#pragma unroll
                for (int ni = 0; ni < 2; ni++) {
                    float a = acc[mi][ni][r], b = acc[mi][ni + 2][r];
                    float sig = 1.f / (1.f + __expf(-a));
                    hrow[ni * 16 + cc] = f2b(a * sig * b);
                }
            } else {
#pragma unroll
                for (int ni = 0; ni < 4; ni++) {
                    long gcol = col0 + wn * 64 + ni * 16 + cc;
                    float v = acc[mi][ni][r];
                    if (OUTMODE == 1)      ((u16*)Cp)[grow * ldo + gcol] = f2b(v);
                    else if (OUTMODE == 2) ((u16*)Cp)[gcol * ldo + grow] = f2b(v);
                    else {
                        float* basep = (float*)(blockIdx.z ? Cp2 : Cp);
                        basep[grow * ldo + gcol] = v;
                    }
                }
            }
        }
    }
}

// ---------------------------------------------------------------------------
// Routed-expert bf16 MFMA GEMM (gathered rows, scaled atomicAdd epilogue)
// ---------------------------------------------------------------------------
__global__ __launch_bounds__(256) void routed_gemm(const u16* __restrict__ Hh,
                                                   const u16* __restrict__ W2T,
                                                   const int* __restrict__ list,
                                                   const float* __restrict__ wlist,
                                                   const int* __restrict__ bases,
                                                   const int* __restrict__ counts,
                                                   float* __restrict__ Cout) {
    const int e    = blockIdx.y >> 5;
    const int tile = blockIdx.y & 31;
    const int cnt  = counts[e];
    if (tile * 128 >= cnt) return;
    const int base = bases[e];

    __shared__ u16 As[128 * 32];
    __shared__ u16 Bs[128 * 32];
    __shared__ int   toks[128];
    __shared__ float wrow[128];

    const int tid = threadIdx.x;
    if (tid < 128) {
        int ridx = tile * 128 + tid;
        if (ridx < cnt) { toks[tid] = list[base + ridx]; wrow[tid] = wlist[base + ridx]; }
        else            { toks[tid] = -1;                wrow[tid] = 0.f; }
    }
    __syncthreads();

    const int lane = tid & 63;
    const int wv   = tid >> 6;
    const int wm   = wv >> 1, wn = wv & 1;
    const long col0 = (long)blockIdx.x * 128;

    f32x4 acc[4][4];
#pragma unroll
    for (int i = 0; i < 4; i++)
#pragma unroll
        for (int j = 0; j < 4; j++) acc[i][j] = (f32x4){0.f, 0.f, 0.f, 0.f};

    const int sr = tid >> 2;
    const int sc = (tid & 3) << 3;
    const int t1 = toks[sr], t2 = toks[sr + 64];
    const u16* Ag  = Hh + (long)(t1 < 0 ? 0 : t1) * HID_ + sc;
    const u16* Ag2 = Hh + (long)(t2 < 0 ? 0 : t2) * HID_ + sc;
    const u16* Bg  = W2T + (long)e * D_ * HID_ + (col0 + sr) * (long)HID_ + sc;
    const u16* Bg2 = Bg + 64 * (long)HID_;
    u16* lA  = As + tid * 8;
    u16* lA2 = As + 2048 + tid * 8;
    u16* lB  = Bs + tid * 8;
    u16* lB2 = Bs + 2048 + tid * 8;

    const int fl = lane & 15;
    const int fk = (lane >> 4) << 3;
    const u16* ArA = As + (wm * 64 + fl) * 32 + fk;
    const u16* BrB = Bs + (wn * 64 + fl) * 32 + fk;

    for (int k0 = 0; k0 < HID_; k0 += 32) {
        __syncthreads();
        g2l16(Ag + k0, lA);
        g2l16(Ag2 + k0, lA2);
        g2l16(Bg + k0, lB);
        g2l16(Bg2 + k0, lB2);
        __syncthreads();
        bf16x8 af[4], bfr[4];
#pragma unroll
        for (int mi = 0; mi < 4; mi++) af[mi]  = *(const bf16x8*)(ArA + mi * 512);
#pragma unroll
        for (int ni = 0; ni < 4; ni++) bfr[ni] = *(const bf16x8*)(BrB + ni * 512);
#pragma unroll
        for (int mi = 0; mi < 4; mi++)
#pragma unroll
            for (int ni = 0; ni < 4; ni++)
                acc[mi][ni] = __builtin_amdgcn_mfma_f32_16x16x32_bf16(
                    af[mi], bfr[ni], acc[mi][ni], 0, 0, 0);
    }

    const int cr = (lane >> 4) << 2;
    const int cc = lane & 15;
#pragma unroll
    for (int mi = 0; mi < 4; mi++) {
#pragma unroll
        for (int r = 0; r < 4; r++) {
            int rr = wm * 64 + mi * 16 + cr + r;
            int tk = toks[rr];
            if (tk < 0) continue;
            float wvw = wrow[rr];
            float* crow = Cout + (long)tk * D_ + col0 + wn * 64;
#pragma unroll
            for (int ni = 0; ni < 4; ni++)
                atomicAdd(crow + ni * 16 + cc, acc[mi][ni][r] * wvw);
        }
    }
}

// ---------------------------------------------------------------------------
// RoPE: sincos table (T_ x 32) then vectorized apply on q,k cols of qkv.
// ---------------------------------------------------------------------------
__global__ __launch_bounds__(256) void rope_table(float2* __restrict__ tab) {
    int idx = blockIdx.x * 256 + threadIdx.x;     // 65536
    int t = idx >> 5, i = idx & 31;
    float ang = (float)t * powf(10000.f, -(float)i / 32.f);
    float sn, cs;
    sincosf(ang, &sn, &cs);
    tab[idx] = make_float2(sn, cs);
}

__global__ __launch_bounds__(256) void rope_apply(u16* __restrict__ qkv,
                                                  const float2* __restrict__ tab) {
    long p = (long)blockIdx.x * 256 + threadIdx.x;   // S_*2048/8 groups
    int s  = (int)(p >> 8);
    int c8 = (int)(p & 255) << 3;
    int t  = s & (T_ - 1);
    const float2* tp = tab + t * 32 + ((c8 & 63) >> 1);
    u16* px = qkv + (long)s * QKVW_ + c8;
    bf16x8 v = *(const bf16x8*)px;
    bf16x8 o;
#pragma unroll
    for (int j = 0; j < 4; j++) {
        float x1 = b2f((u16)v[2 * j]), x2 = b2f((u16)v[2 * j + 1]);
        float2 sc = tp[j];
        o[2 * j]     = (short)f2b(x1 * sc.y - x2 * sc.x);
        o[2 * j + 1] = (short)f2b(x1 * sc.x + x2 * sc.y);
    }
    *(bf16x8*)px = o;
}

// ---------------------------------------------------------------------------
// MFMA flash attention, 128-key x 128-query tiles. grid (T/128, B*H),
// 512 thr = 8 waves x 16 q-rows.
// v2: K double-buffered in LDS with prefetch (one barrier per tile, staging
//     loads in flight across the whole compute phase); V read directly from
//     global (16KB tile L1-resident after first wave); bijective XCD swizzle
//     so each XCD owns 4 heads (K/V 2MB < 4MB L2); setprio around MFMA.
// LDS: Ks 2x128x64 + Ps 8x16x128 = 64KB -> 2 blocks/CU, grid 512 = 2/CU.
// ---------------------------------------------------------------------------
__global__ __launch_bounds__(512) void attn_kernel(const u16* __restrict__ qkv,
                                                   const u16* __restrict__ vtg,
                                                   u16* __restrict__ sab) {
    __shared__ u16 Ks[2][128 * 64];
    __shared__ u16 Ps[8][16 * 128];
    const int tid  = threadIdx.x;
    const int lane = tid & 63;
    const int w    = tid >> 6;          // 0..7
    // XCD-aware bijective swizzle: flat 0..511, xcd = flat&7 gets 64
    // consecutive virtual ids = 4 bh * 16 qtiles.
    const int flat = blockIdx.x + (blockIdx.y << 4);
    const int virt = ((flat & 7) << 6) | (flat >> 3);
    const int qt = virt & 15;
    const int bh = virt >> 4;
    const int b  = bh >> 4, h = bh & 15;
    const long tok0 = (long)b * T_ + qt * 128;
    const int fl = lane & 15;
    const int fq = lane >> 4;

    bf16x8 qf0, qf1;
    {
        const u16* qp = qkv + (tok0 + w * 16 + fl) * QKVW_ + h * 64 + fq * 8;
        qf0 = *(const bf16x8*)qp;
        qf1 = *(const bf16x8*)(qp + 32);
    }

    const u16* kb0 = qkv + ((long)b * T_) * QKVW_ + 1024 + h * 64;
    const u16* vb0 = vtg + ((long)bh * 64) * T_;

    float m_[4], l_[4];
    f32x4 oacc[4];
#pragma unroll
    for (int i = 0; i < 4; i++) {
        m_[i] = -1e30f; l_[i] = 0.f;
        oacc[i] = (f32x4){0.f, 0.f, 0.f, 0.f};
    }

    // K staging: 1024 slots (row=i>>3 of 128 keys, grp=i&7), 2 passes of 512,
    // source column pre-swizzled so LDS stays linear (g2l16 constraint).
    auto stageK = [&](int kt, int buf) {
#pragma unroll
        for (int ps = 0; ps < 2; ps++) {
            int i = tid + ps * 512;
            int row = i >> 3, gg = i & 7;
            g2l16(kb0 + (long)(kt * 128 + row) * QKVW_ + ((gg ^ (row & 7)) << 3),
                  Ks[buf] + i * 8);
        }
    };

    stageK(0, 0);
    int cur = 0;
    for (int kt = 0; kt < T_ / 128; kt++) {
        // drains vmcnt: K(kt) landed (loads had the whole previous compute
        // phase in flight); also all waves done reading Ks[cur^1].
        __syncthreads();
        if (kt + 1 < T_ / 128) stageK(kt + 1, cur ^ 1);
        const u16* kbase = Ks[cur];

        // S = Q K^T  (16 q-rows x 128 k-cols per wave)
        f32x4 sacc[8];
#pragma unroll
        for (int ni = 0; ni < 8; ni++) sacc[ni] = (f32x4){0.f, 0.f, 0.f, 0.f};
        __builtin_amdgcn_s_setprio(1);
#pragma unroll
        for (int ks = 0; ks < 2; ks++) {
            bf16x8 qq = ks ? qf1 : qf0;
#pragma unroll
            for (int ni = 0; ni < 8; ni++) {
                bf16x8 kf = *(const bf16x8*)(kbase + (ni * 16 + fl) * 64 +
                                             (((ks * 4 + fq) ^ (fl & 7)) << 3));
                sacc[ni] = __builtin_amdgcn_mfma_f32_16x16x32_bf16(qq, kf, sacc[ni], 0, 0, 0);
            }
        }
        __builtin_amdgcn_s_setprio(0);

        float rmax[4];
#pragma unroll
        for (int r = 0; r < 4; r++) {
            float mm = sacc[0][r];
#pragma unroll
            for (int ni = 1; ni < 8; ni++) mm = fmaxf(mm, sacc[ni][r]);
            rmax[r] = mm * 0.125f;
        }
#pragma unroll
        for (int off = 1; off < 16; off <<= 1)
#pragma unroll
            for (int r = 0; r < 4; r++) rmax[r] = fmaxf(rmax[r], __shfl_xor(rmax[r], off));
        float alpha[4], psum[4];
#pragma unroll
        for (int r = 0; r < 4; r++) {
            float nm = fmaxf(m_[r], rmax[r]);
            alpha[r] = __expf(m_[r] - nm);
            m_[r] = nm;
            psum[r] = 0.f;
        }
        u16* pst = Ps[w];
#pragma unroll
        for (int ni = 0; ni < 8; ni++) {
            int colg = ni * 2 + (fl >> 3);
            int cl   = fl & 7;
#pragma unroll
            for (int r = 0; r < 4; r++) {
                int row = fq * 4 + r;
                float p = __expf(sacc[ni][r] * 0.125f - m_[r]);
                psum[r] += p;
                pst[row * 128 + ((colg ^ (row & 15)) << 3) + cl] = f2b(p);
            }
        }
#pragma unroll
        for (int off = 1; off < 16; off <<= 1)
#pragma unroll
            for (int r = 0; r < 4; r++) psum[r] += __shfl_xor(psum[r], off);
#pragma unroll
        for (int r = 0; r < 4; r++) l_[r] = l_[r] * alpha[r] + psum[r];
#pragma unroll
        for (int ni = 0; ni < 4; ni++)
#pragma unroll
            for (int r = 0; r < 4; r++) oacc[ni][r] *= alpha[r];

        // O += P V   (K=128 over 4 ks steps); V direct from global (L1/L2).
        __builtin_amdgcn_s_setprio(1);
#pragma unroll
        for (int ks = 0; ks < 4; ks++) {
            bf16x8 pf = *(const bf16x8*)(pst + fl * 128 +
                                         (((ks * 4 + fq) ^ fl) << 3));
#pragma unroll
            for (int ni = 0; ni < 4; ni++) {
                const u16* vp = vb0 + (long)(ni * 16 + fl) * T_ + kt * 128 +
                                ((ks * 4 + fq) << 3);
                bf16x8 vf = *(const bf16x8*)vp;
                oacc[ni] = __builtin_amdgcn_mfma_f32_16x16x32_bf16(pf, vf, oacc[ni], 0, 0, 0);
            }
        }
        __builtin_amdgcn_s_setprio(0);
        cur ^= 1;
    }

#pragma unroll
    for (int r = 0; r < 4; r++) {
        float inv = 1.f / l_[r];
        u16* op = sab + (tok0 + w * 16 + fq * 4 + r) * D_ + h * 64 + fl;
#pragma unroll
        for (int ni = 0; ni < 4; ni++) op[ni * 16] = f2b(oacc[ni][r] * inv);
    }
}

// ---------------------------------------------------------------------------
// Residual add (3 inputs) + RMSNorm. BF=1 additionally writes bf16 copy.
// ---------------------------------------------------------------------------
template<int BF>
__global__ __launch_bounds__(256) void rmsnorm_res(const float* __restrict__ a,
                                                   const float* __restrict__ b,
                                                   const float* __restrict__ b2,
                                                   const float* __restrict__ w,
                                                   float* __restrict__ outf,
                                                   u16* __restrict__ outb) {
    const int s = blockIdx.x;
    const float* ar = a + (long)s * D_;
    const float* br = b + (long)s * D_;
    const float* cr2 = b2 + (long)s * D_;
    float y[4];
    float ss = 0.f;
#pragma unroll
    for (int kx = 0; kx < 4; kx++) {
        int j = threadIdx.x + kx * 256;
        y[kx] = ar[j] + br[j] + cr2[j];
        ss += y[kx] * y[kx];
    }
    __shared__ float red[4];
#pragma unroll
    for (int off = 32; off > 0; off >>= 1) ss += __shfl_down(ss, off);
    int lane = threadIdx.x & 63, wv = threadIdx.x >> 6;
    if (lane == 0) red[wv] = ss;
    __syncthreads();
    float tot = red[0] + red[1] + red[2] + red[3];
    float scl = rsqrtf(tot / (float)D_ + EPS_);
    float* orow = outf + (long)s * D_;
#pragma unroll
    for (int kx = 0; kx < 4; kx++) {
        int j = threadIdx.x + kx * 256;
        float v = y[kx] * scl * w[j];
        orow[j] = v;
        if (BF) outb[(long)s * D_ + j] = f2b(v);
    }
}

// ---------------------------------------------------------------------------
// Gating (fp32): one wave per token. Writes per-token top-2 (expert, weight).
// ---------------------------------------------------------------------------
__global__ __launch_bounds__(256) void gate_kernel(const float* __restrict__ x,
                                                   const float* __restrict__ Wg,
                                                   const float* __restrict__ We,
                                                   const float* __restrict__ gb,
                                                   const float* __restrict__ eb,
                                                   int* __restrict__ tok_e,
                                                   float* __restrict__ tok_w) {
    const int wave = threadIdx.x >> 6;
    const int lane = threadIdx.x & 63;
    const int s = blockIdx.x * 4 + wave;
    const float* xr = x + (long)s * D_;
    float g0 = 0.f, g1 = 0.f;
    float ee[8];
#pragma unroll
    for (int e = 0; e < 8; e++) ee[e] = 0.f;
    for (int j = lane; j < D_; j += 64) {
        float xv = xr[j];
        g0 += xv * Wg[j * 2 + 0];
        g1 += xv * Wg[j * 2 + 1];
#pragma unroll
        for (int e = 0; e < 8; e++) ee[e] += xv * We[j * 8 + e];
    }
#pragma unroll
    for (int off = 32; off > 0; off >>= 1) {
        g0 += __shfl_down(g0, off);
        g1 += __shfl_down(g1, off);
#pragma unroll
        for (int e = 0; e < 8; e++) ee[e] += __shfl_down(ee[e], off);
    }
    if (lane == 0) {
        g0 += gb[0];
        g1 += gb[1];
        int gidx = (g1 > g0) ? 1 : 0;
        float gm = fmaxf(g0, g1);
        float p0 = expf(g0 - gm), p1 = expf(g1 - gm);
        float gprob = (gidx ? p1 : p0) / (p0 + p1);
        int base = gidx * 4;
        float pe[4];
        float em = -1e30f;
#pragma unroll
        for (int i = 0; i < 4; i++) {
            pe[i] = ee[base + i] + eb[base + i];
            em = fmaxf(em, pe[i]);
        }
        float sum = 0.f;
#pragma unroll
        for (int i = 0; i < 4; i++) { pe[i] = expf(pe[i] - em); sum += pe[i]; }
        float inv = gprob / sum;
#pragma unroll
        for (int i = 0; i < 4; i++) pe[i] *= inv;
        int i1 = 0;
        for (int i = 1; i < 4; i++) if (pe[i] > pe[i1]) i1 = i;
        int i2 = -1;
        for (int i = 0; i < 4; i++) {
            if (i == i1) continue;
            if (i2 < 0 || pe[i] > pe[i2]) i2 = i;
        }
        tok_e[s * 2 + 0] = base + i1;
        tok_e[s * 2 + 1] = base + i2;
        tok_w[s * 2 + 0] = pe[i1];
        tok_w[s * 2 + 1] = pe[i2];
    }
}

// ---------------------------------------------------------------------------
// Single-block routing build: histogram + scan + scatter in LDS.
// ---------------------------------------------------------------------------
__global__ __launch_bounds__(256) void route_build(const int* __restrict__ tok_e,
                                                   const float* __restrict__ tok_w,
                                                   int* __restrict__ counts_g,
                                                   int* __restrict__ bases_g,
                                                   int* __restrict__ list,
                                                   float* __restrict__ wlist) {
    __shared__ int cnt[E_], bas[E_], cur[E_];
    const int tid = threadIdx.x;
    if (tid < E_) cnt[tid] = 0;
    __syncthreads();
    for (int i = tid; i < 2 * S_; i += 256) atomicAdd(&cnt[tok_e[i]], 1);
    __syncthreads();
    if (tid == 0) {
        int acc = 0;
        for (int e = 0; e < E_; e++) { bas[e] = acc; cur[e] = acc; acc += cnt[e]; }
    }
    __syncthreads();
    if (tid < E_) { counts_g[tid] = cnt[tid]; bases_g[tid] = bas[tid]; }
    for (int i = tid; i < 2 * S_; i += 256) {
        int e = tok_e[i];
        int p = atomicAdd(&cur[e], 1);
        list[p] = i >> 1;
        wlist[p] = tok_w[i];
    }
}

// ---------------------------------------------------------------------------
extern "C" void kernel_launch(void* const* d_in, const int* in_sizes, int n_in,
                              void* d_out, int out_size, void* d_ws, size_t ws_size,
                              hipStream_t stream) {
    const float* src  = (const float*)d_in[0];
    const float* Wq   = (const float*)d_in[1];
    const float* Wk_c = (const float*)d_in[2];
    const float* Wv_c = (const float*)d_in[3];
    const float* Wk   = (const float*)d_in[4];
    const float* Wv   = (const float*)d_in[5];
    const float* Wo   = (const float*)d_in[6];
    const float* Wsin = (const float*)d_in[7];
    const float* Wsout= (const float*)d_in[8];
    const float* W1   = (const float*)d_in[9];
    const float* W2   = (const float*)d_in[10];
    const float* Wg   = (const float*)d_in[11];
    const float* We   = (const float*)d_in[12];
    const float* gb   = (const float*)d_in[13];
    const float* eb   = (const float*)d_in[14];
    const float* n1w  = (const float*)d_in[15];
    const float* n2w  = (const float*)d_in[16];
    float* out = (float*)d_out;

    const size_t MB = 1u << 20;
    char* w8 = (char*)d_ws;
    // Layout (MiB offsets). Lifetimes:
    u16*  qkv   = (u16*)(w8);              // 0..24; dead after attn
    u16*  vtg   = (u16*)(w8 + 24 * MB);    // 24..32; dead after attn
    float* oproj0 = (float*)(w8);          // 0..16 (after attn; dead after rmsnorm1)
    float* oproj1 = (float*)(w8 + 16 * MB);// 16..32 (same)
    u16*  w2t   = (u16*)(w8);              // 0..32 (after rmsnorm1)
    u16*  WkcB  = (u16*)(w8 + 24 * MB);    // early temps (dead before vt_conv)
    u16*  WvcB  = (u16*)(w8 + 24 * MB + 512 * 1024);
    u16*  WkTs  = (u16*)(w8 + 25 * MB);
    u16*  WvTs  = (u16*)(w8 + 25 * MB + 512 * 1024);
    u16*  sab   = (u16*)(w8 + 32 * MB);    // 32..40; dead after Wo gemm
    float* tokw = (float*)(w8 + 32 * MB);  // gating arrays overlay dead sab
    float* wlist = tokw + 2 * S_;
    int* toke   = (int*)(wlist + 2 * S_);
    int* list   = toke + 2 * S_;
    int* counts = list + 2 * S_;
    int* bases  = counts + E_;
    float* x1   = (float*)(w8 + 40 * MB);  // 40..56
    float* ffn0 = (float*)(w8 + 56 * MB);  // 56..72
    u16*  x1b   = (u16*)(w8 + 72 * MB);    // 72..80 (dead after FFN-in gemm)
    u16*  hbuf  = (u16*)(w8 + 80 * MB);    // 80..96 (shared-FFN h)
    u16*  srcb  = (u16*)(w8 + 96 * MB);    // 96..104 (early; dead after QKV gemm)
    float2* rtab= (float2*)(w8 + 104 * MB);// 104..104.5 (dead after rope_apply)
    u16*  hbuf2 = (u16*)(w8 + 96 * MB);    // 96..112 (routed h; after srcb/rtab dead)
    u16*  WqkvT = (u16*)(w8 + 112 * MB);   // 112..118 (early)
    u16*  WsoutT= (u16*)(w8 + 112 * MB);   // 112..116 (after WqkvT dead)
    u16*  WoT   = (u16*)(w8 + 118 * MB);   // 118..120
    u16*  WsinT = (u16*)(w8 + 120 * MB);   // 120..128 (dead after FFN-in)
    u16*  W1T   = (u16*)(w8 + 128 * MB);   // 128..136 (dead after FFN-in)
    float* ffn1 = (float*)(w8 + 120 * MB); // 120..136 (overlays WsinT/W1T, late)

    dim3 blk(256);

    // --- build fused QKV weight (3072 x 1024 bf16, Bt layout) ---
    conv_t<<<dim3(32, 32), blk, 0, stream>>>(Wq, WqkvT, 1024, 1024, 0, 0, 0);
    convert_bf16<<<dim3(D_ * DC_ / 4 / 256), blk, 0, stream>>>(Wk_c, WkcB, D_ * DC_ / 4);
    convert_bf16<<<dim3(D_ * DC_ / 4 / 256), blk, 0, stream>>>(Wv_c, WvcB, D_ * DC_ / 4);
    conv_t<<<dim3(32, 8), blk, 0, stream>>>(Wk, WkTs, 256, 1024, 0, 0, 0);
    conv_t<<<dim3(32, 8), blk, 0, stream>>>(Wv, WvTs, 256, 1024, 0, 0, 0);
    gemm_bf16<2><<<dim3(8, 8), blk, 0, stream>>>(WkcB, WkTs, WqkvT + 1024 * 1024, 1024, 256, 1024, nullptr);
    gemm_bf16<2><<<dim3(8, 8), blk, 0, stream>>>(WvcB, WvTs, WqkvT + 2048 * 1024, 1024, 256, 1024, nullptr);

    convert_bf16<<<dim3(S_ * D_ / 4 / 256), blk, 0, stream>>>(src, srcb, S_ * D_ / 4);

    // Fused QKV projection: (S,1024) @ (1024,3072) -> qkv (S,3072)
    gemm_bf16<1><<<dim3(24, 32), blk, 0, stream>>>(srcb, WqkvT, qkv, QKVW_, 1024, QKVW_, nullptr);

    // other weight conversions (WqkvT dead; WsoutT overlays it)
    conv_t<<<dim3(32, 32), blk, 0, stream>>>(Wo, WoT, 1024, 1024, 0, 0, 0);
    conv_t<<<dim3(128, 32), blk, 0, stream>>>(Wsin, WsinT, 1024, 4096, 0, 0, 1);
    conv_t<<<dim3(32, 64), blk, 0, stream>>>(Wsout, WsoutT, 2048, 1024, 0, 0, 0);
    conv_t<<<dim3(128, 32), blk, 0, stream>>>(W1, W1T, 1024, 4096, 0, 0, 1);

    // RoPE (table + vectorized apply)
    rope_table<<<dim3(T_ * 32 / 256), blk, 0, stream>>>(rtab);
    rope_apply<<<dim3(S_ * 2048 / 8 / 256), blk, 0, stream>>>(qkv, rtab);

    vt_conv<<<dim3(T_ / 32, 2, B_ * H_), blk, 0, stream>>>(qkv, vtg);
    attn_kernel<<<dim3(T_ / 128, B_ * H_), dim3(512), 0, stream>>>(qkv, vtg, sab);

    // Wo projection, split-K=2 plain stores into two buffers
    gemm_bf16<5><<<dim3(8, 32, 2), blk, 0, stream>>>(sab, WoT, oproj0, 1024, 1024, 1024, oproj1);
    rmsnorm_res<1><<<dim3(S_), blk, 0, stream>>>(src, oproj0, oproj1, n1w, x1, x1b);

    // Merged FFN-in (shared + routed W1) with fused swiglu -> hbuf, hbuf2
    gemm_bf16<3><<<dim3(64, 32), blk, 0, stream>>>(x1b, WsinT, hbuf, 8192, 1024, 2048, nullptr);

    // Shared FFN-out, split-K=2 plain stores -> ffn0, ffn1
    gemm_bf16<5><<<dim3(8, 32, 2), blk, 0, stream>>>(hbuf, WsoutT, ffn0, 1024, 2048, 1024, ffn1);

    // Gating + routing lists
    gate_kernel<<<dim3(S_ / 4), blk, 0, stream>>>(x1, Wg, We, gb, eb, toke, tokw);
    route_build<<<dim3(1), blk, 0, stream>>>(toke, tokw, counts, bases, list, wlist);

    // Routed experts: W2 transpose, gathered GEMM atomicAdd onto ffn0
    conv_t<<<dim3(32, 64, 8), blk, 0, stream>>>(W2, w2t, 2048, 1024,
                                                (long)HID_ * D_, (long)D_ * HID_, 0);
    routed_gemm<<<dim3(8, E_ * 32), blk, 0, stream>>>(hbuf2, w2t, list, wlist,
                                                      bases, counts, ffn0);

    rmsnorm_res<0><<<dim3(S_), blk, 0, stream>>>(x1, ffn0, ffn1, n2w, out, (u16*)nullptr);
}

// Round 2
// 694.536 us; speedup vs baseline: 1.0961x; 1.0961x over previous
//
#include <hip/hip_runtime.h>
#include <math.h>

#define D_    1024
#define H_    16
#define DH_   64
#define DC_   256
#define HID_  2048
#define E_    8
#define B_    2
#define T_    2048
#define S_    4096
#define EPS_  1e-6f
#define QKVW_ 3072   // fused qkv row width

typedef unsigned short u16;
typedef short bf16x8 __attribute__((ext_vector_type(8)));
typedef float f32x4 __attribute__((ext_vector_type(4)));

__device__ __forceinline__ float b2f(u16 u) {
    return __uint_as_float(((unsigned int)u) << 16);
}
__device__ __forceinline__ u16 f2b(float f) {
    unsigned int u = __float_as_uint(f);
    u += 0x7FFF + ((u >> 16) & 1);
    return (u16)(u >> 16);
}
__device__ __forceinline__ void g2l16(const u16* g, u16* l) {
    __builtin_amdgcn_global_load_lds(
        (const __attribute__((address_space(1))) void*)g,
        (__attribute__((address_space(3))) void*)l, 16, 0, 0);
}

// ---------------------------------------------------------------------------
// Transpose + fp32->bf16: in (K,N) fp32 -> out (N,K) bf16.
// perm=1: swiglu column interleave for fused epilogue.
// ---------------------------------------------------------------------------
__global__ __launch_bounds__(256) void conv_t(const float* __restrict__ in,
                                              u16* __restrict__ out,
                                              int K, int N,
                                              long inZ, long outZ, int perm) {
    in  += (long)blockIdx.z * inZ;
    out += (long)blockIdx.z * outZ;
    __shared__ float t[32][33];
    const int n0 = blockIdx.x * 32, k0 = blockIdx.y * 32;
    int src_n0 = n0;
    if (perm) {
        int t64 = n0 >> 6;
        src_n0 = ((n0 & 63) == 0) ? t64 * 32 : (N / 2 + t64 * 32);
    }
    const int tx = threadIdx.x & 31, ty = threadIdx.x >> 5;
#pragma unroll
    for (int i = 0; i < 4; i++)
        t[ty + 8 * i][tx] = in[(long)(k0 + ty + 8 * i) * N + src_n0 + tx];
    __syncthreads();
#pragma unroll
    for (int i = 0; i < 4; i++)
        out[(long)(n0 + ty + 8 * i) * K + k0 + tx] = f2b(t[tx][ty + 8 * i]);
}

// bf16 transpose V rows of fused qkv (stride QKVW_) per-head -> Vt [bh][64][T]
__global__ __launch_bounds__(256) void vt_conv(const u16* __restrict__ qkv,
                                               u16* __restrict__ vt) {
    __shared__ u16 t[32][34];
    const int bh = blockIdx.z;
    const int b = bh >> 4, h = bh & 15;
    const int t0 = blockIdx.x * 32, d0 = blockIdx.y * 32;
    const int tx = threadIdx.x & 31, ty = threadIdx.x >> 5;
#pragma unroll
    for (int i = 0; i < 4; i++)
        t[ty + 8 * i][tx] =
            qkv[((long)b * T_ + t0 + ty + 8 * i) * QKVW_ + 2048 + h * 64 + d0 + tx];
    __syncthreads();
#pragma unroll
    for (int i = 0; i < 4; i++)
        vt[((long)bh * 64 + d0 + ty + 8 * i) * T_ + t0 + tx] = t[tx][ty + 8 * i];
}

// Elementwise fp32 -> bf16
__global__ __launch_bounds__(256) void convert_bf16(const float* __restrict__ in,
                                                    u16* __restrict__ out, int n4) {
    int i = blockIdx.x * 256 + threadIdx.x;
    if (i >= n4) return;
    float4 f = ((const float4*)in)[i];
    ushort4 o;
    o.x = f2b(f.x); o.y = f2b(f.y); o.z = f2b(f.z); o.w = f2b(f.w);
    ((ushort4*)out)[i] = o;
}

// ---------------------------------------------------------------------------
// bf16 MFMA GEMM: C(M,N) = A(M,K) @ Bt(N,K)^T. 128x128, BK=32, 4 waves.
// OUTMODE 1: bf16 store | 2: bf16 transposed store (ldo=M)
// OUTMODE 3: swiglu epilogue, dual output: blockIdx.x>=32 -> Cp + S_*HID_
// OUTMODE 5: split-K (gridDim.z=2), fp32 plain store; z=0 -> Cp, z=1 -> Cp2
// ---------------------------------------------------------------------------
template<int OUTMODE>
__global__ __launch_bounds__(256) void gemm_bf16(const u16* __restrict__ A,
                                                 const u16* __restrict__ Bt,
                                                 void* __restrict__ Cp,
                                                 int N, int K, int ldo,
                                                 void* __restrict__ Cp2) {
    __shared__ u16 As[128 * 32];
    __shared__ u16 Bs[128 * 32];
    const int tid  = threadIdx.x;
    const int lane = tid & 63;
    const int wv   = tid >> 6;
    const int wm   = wv >> 1, wn = wv & 1;
    const long row0 = (long)blockIdx.y * 128;
    const long col0 = (long)blockIdx.x * 128;
    const int Klocal = K / gridDim.z;
    const long koff  = (long)blockIdx.z * Klocal;

    f32x4 acc[4][4];
#pragma unroll
    for (int i = 0; i < 4; i++)
#pragma unroll
        for (int j = 0; j < 4; j++) acc[i][j] = (f32x4){0.f, 0.f, 0.f, 0.f};

    const int sr = tid >> 2;
    const int sc = (tid & 3) << 3;
    const u16* Ag  = A  + (row0 + sr) * (long)K + koff + sc;
    const u16* Ag2 = Ag + 64 * (long)K;
    const u16* Bg  = Bt + (col0 + sr) * (long)K + koff + sc;
    const u16* Bg2 = Bg + 64 * (long)K;
    u16* lA  = As + tid * 8;
    u16* lA2 = As + 2048 + tid * 8;
    u16* lB  = Bs + tid * 8;
    u16* lB2 = Bs + 2048 + tid * 8;

    const int fl = lane & 15;
    const int fk = (lane >> 4) << 3;
    const u16* ArA = As + (wm * 64 + fl) * 32 + fk;
    const u16* BrB = Bs + (wn * 64 + fl) * 32 + fk;

    for (int k0 = 0; k0 < Klocal; k0 += 32) {
        __syncthreads();
        g2l16(Ag + k0, lA);
        g2l16(Ag2 + k0, lA2);
        g2l16(Bg + k0, lB);
        g2l16(Bg2 + k0, lB2);
        __syncthreads();
        bf16x8 af[4], bfr[4];
#pragma unroll
        for (int mi = 0; mi < 4; mi++) af[mi]  = *(const bf16x8*)(ArA + mi * 512);
#pragma unroll
        for (int ni = 0; ni < 4; ni++) bfr[ni] = *(const bf16x8*)(BrB + ni * 512);
#pragma unroll
        for (int mi = 0; mi < 4; mi++)
#pragma unroll
            for (int ni = 0; ni < 4; ni++)
                acc[mi][ni] = __builtin_amdgcn_mfma_f32_16x16x32_bf16(
                    af[mi], bfr[ni], acc[mi][ni], 0, 0, 0);
    }

    const int cr = (lane >> 4) << 2;
    const int cc = lane & 15;
#pragma unroll
    for (int mi = 0; mi < 4; mi++) {
#pragma unroll
        for (int r = 0; r < 4; r++) {
            long grow = row0 + wm * 64 + mi * 16 + cr + r;
            if (OUTMODE == 3) {
                u16* outb = (u16*)Cp + (long)(blockIdx.x >> 5) * S_ * HID_;
                u16* hrow = outb + grow * ldo + (blockIdx.x & 31) * 64 + wn * 32;
#pragma unroll
                for (int ni = 0; ni < 2; ni++) {
                    float a = acc[mi][ni][r], b = acc[mi][ni + 2][r];
                    float sig = 1.f / (1.f + __expf(-a));
                    hrow[ni * 16 + cc] = f2b(a * sig * b);
                }
            } else {
#pragma unroll
                for (int ni = 0; ni < 4; ni++) {
                    long gcol = col0 + wn * 64 + ni * 16 + cc;
                    float v = acc[mi][ni][r];
                    if (OUTMODE == 1)      ((u16*)Cp)[grow * ldo + gcol] = f2b(v);
                    else if (OUTMODE == 2) ((u16*)Cp)[gcol * ldo + grow] = f2b(v);
                    else {
                        float* basep = (float*)(blockIdx.z ? Cp2 : Cp);
                        basep[grow * ldo + gcol] = v;
                    }
                }
            }
        }
    }
}

// ---------------------------------------------------------------------------
// Routed-expert bf16 MFMA GEMM (gathered rows, scaled atomicAdd epilogue)
// ---------------------------------------------------------------------------
__global__ __launch_bounds__(256) void routed_gemm(const u16* __restrict__ Hh,
                                                   const u16* __restrict__ W2T,
                                                   const int* __restrict__ list,
                                                   const float* __restrict__ wlist,
                                                   const int* __restrict__ bases,
                                                   const int* __restrict__ counts,
                                                   float* __restrict__ Cout) {
    const int e    = blockIdx.y >> 5;
    const int tile = blockIdx.y & 31;
    const int cnt  = counts[e];
    if (tile * 128 >= cnt) return;
    const int base = bases[e];

    __shared__ u16 As[128 * 32];
    __shared__ u16 Bs[128 * 32];
    __shared__ int   toks[128];
    __shared__ float wrow[128];

    const int tid = threadIdx.x;
    if (tid < 128) {
        int ridx = tile * 128 + tid;
        if (ridx < cnt) { toks[tid] = list[base + ridx]; wrow[tid] = wlist[base + ridx]; }
        else            { toks[tid] = -1;                wrow[tid] = 0.f; }
    }
    __syncthreads();

    const int lane = tid & 63;
    const int wv   = tid >> 6;
    const int wm   = wv >> 1, wn = wv & 1;
    const long col0 = (long)blockIdx.x * 128;

    f32x4 acc[4][4];
#pragma unroll
    for (int i = 0; i < 4; i++)
#pragma unroll
        for (int j = 0; j < 4; j++) acc[i][j] = (f32x4){0.f, 0.f, 0.f, 0.f};

    const int sr = tid >> 2;
    const int sc = (tid & 3) << 3;
    const int t1 = toks[sr], t2 = toks[sr + 64];
    const u16* Ag  = Hh + (long)(t1 < 0 ? 0 : t1) * HID_ + sc;
    const u16* Ag2 = Hh + (long)(t2 < 0 ? 0 : t2) * HID_ + sc;
    const u16* Bg  = W2T + (long)e * D_ * HID_ + (col0 + sr) * (long)HID_ + sc;
    const u16* Bg2 = Bg + 64 * (long)HID_;
    u16* lA  = As + tid * 8;
    u16* lA2 = As + 2048 + tid * 8;
    u16* lB  = Bs + tid * 8;
    u16* lB2 = Bs + 2048 + tid * 8;

    const int fl = lane & 15;
    const int fk = (lane >> 4) << 3;
    const u16* ArA = As + (wm * 64 + fl) * 32 + fk;
    const u16* BrB = Bs + (wn * 64 + fl) * 32 + fk;

    for (int k0 = 0; k0 < HID_; k0 += 32) {
        __syncthreads();
        g2l16(Ag + k0, lA);
        g2l16(Ag2 + k0, lA2);
        g2l16(Bg + k0, lB);
        g2l16(Bg2 + k0, lB2);
        __syncthreads();
        bf16x8 af[4], bfr[4];
#pragma unroll
        for (int mi = 0; mi < 4; mi++) af[mi]  = *(const bf16x8*)(ArA + mi * 512);
#pragma unroll
        for (int ni = 0; ni < 4; ni++) bfr[ni] = *(const bf16x8*)(BrB + ni * 512);
#pragma unroll
        for (int mi = 0; mi < 4; mi++)
#pragma unroll
            for (int ni = 0; ni < 4; ni++)
                acc[mi][ni] = __builtin_amdgcn_mfma_f32_16x16x32_bf16(
                    af[mi], bfr[ni], acc[mi][ni], 0, 0, 0);
    }

    const int cr = (lane >> 4) << 2;
    const int cc = lane & 15;
#pragma unroll
    for (int mi = 0; mi < 4; mi++) {
#pragma unroll
        for (int r = 0; r < 4; r++) {
            int rr = wm * 64 + mi * 16 + cr + r;
            int tk = toks[rr];
            if (tk < 0) continue;
            float wvw = wrow[rr];
            float* crow = Cout + (long)tk * D_ + col0 + wn * 64;
#pragma unroll
            for (int ni = 0; ni < 4; ni++)
                atomicAdd(crow + ni * 16 + cc, acc[mi][ni][r] * wvw);
        }
    }
}

// ---------------------------------------------------------------------------
// RoPE: sincos table (T_ x 32) then vectorized apply on q,k cols of qkv.
// ---------------------------------------------------------------------------
__global__ __launch_bounds__(256) void rope_table(float2* __restrict__ tab) {
    int idx = blockIdx.x * 256 + threadIdx.x;     // 65536
    int t = idx >> 5, i = idx & 31;
    float ang = (float)t * powf(10000.f, -(float)i / 32.f);
    float sn, cs;
    sincosf(ang, &sn, &cs);
    tab[idx] = make_float2(sn, cs);
}

__global__ __launch_bounds__(256) void rope_apply(u16* __restrict__ qkv,
                                                  const float2* __restrict__ tab) {
    long p = (long)blockIdx.x * 256 + threadIdx.x;   // S_*2048/8 groups
    int s  = (int)(p >> 8);
    int c8 = (int)(p & 255) << 3;
    int t  = s & (T_ - 1);
    const float2* tp = tab + t * 32 + ((c8 & 63) >> 1);
    u16* px = qkv + (long)s * QKVW_ + c8;
    bf16x8 v = *(const bf16x8*)px;
    bf16x8 o;
#pragma unroll
    for (int j = 0; j < 4; j++) {
        float x1 = b2f((u16)v[2 * j]), x2 = b2f((u16)v[2 * j + 1]);
        float2 sc = tp[j];
        o[2 * j]     = (short)f2b(x1 * sc.y - x2 * sc.x);
        o[2 * j + 1] = (short)f2b(x1 * sc.x + x2 * sc.y);
    }
    *(bf16x8*)px = o;
}

// ---------------------------------------------------------------------------
// MFMA flash attention, 128-key x 128-query tiles. grid (T/128, B*H),
// 512 thr = 8 waves x 16 q-rows.
// v3: K AND V staged in LDS (v1 layout, byte-identical addressing) with
//     T14 async-STAGE split: global loads for tile kt+1 ISSUED at top of
//     tile kt's compute (latency hides under 32 MFMA + softmax), ds_write
//     after the post-compute barrier. XCD swizzle + setprio + defer-max kept.
// LDS: Ks 16KB + Vs 16KB + Ps 32KB = 64KB -> 2 blocks/CU.
// ---------------------------------------------------------------------------
__global__ __launch_bounds__(512, 4) void attn_kernel(const u16* __restrict__ qkv,
                                                      const u16* __restrict__ vtg,
                                                      u16* __restrict__ sab) {
    __shared__ u16 Ks[128 * 64];
    __shared__ u16 Vs[64 * 128];
    __shared__ u16 Ps[8][16 * 128];
    const int tid  = threadIdx.x;
    const int lane = tid & 63;
    const int w    = tid >> 6;          // 0..7
    // XCD-aware bijective swizzle: flat 0..511; xcd = flat&7 owns 64
    // consecutive virtual ids = 4 bh * 16 qtiles (K/V 2MB < 4MB L2).
    const int flat = blockIdx.x + (blockIdx.y << 4);
    const int virt = ((flat & 7) << 6) | (flat >> 3);
    const int qt = virt & 15;
    const int bh = virt >> 4;
    const int b  = bh >> 4, h = bh & 15;
    const long tok0 = (long)b * T_ + qt * 128;
    const int fl = lane & 15;
    const int fq = lane >> 4;

    bf16x8 qf0, qf1;
    {
        const u16* qp = qkv + (tok0 + w * 16 + fl) * QKVW_ + h * 64 + fq * 8;
        qf0 = *(const bf16x8*)qp;
        qf1 = *(const bf16x8*)(qp + 32);
    }

    const u16* kb0 = qkv + ((long)b * T_) * QKVW_ + 1024 + h * 64;
    const u16* vb0 = vtg + ((long)bh * 64) * T_;

    // ---- T14 register staging: per-thread 4x16B, addressing identical to v1
    // K slots: i = tid / tid+512; row = i>>3 (128 key rows), grp = i&7,
    //          source column XOR-swizzled so LDS stays linear.
    // V slots: i = tid / tid+512; row = i>>4 (64 d rows), grp = i&15.
    const int kr0 = tid >> 3,         kgg = tid & 7;
    const int kr1 = (tid + 512) >> 3;
    const int vr0 = tid >> 4,         vgg = tid & 15;
    const int vr1 = (tid + 512) >> 4;
    const u16* kp0 = kb0 + (long)kr0 * QKVW_ + ((kgg ^ (kr0 & 7)) << 3);
    const u16* kp1 = kb0 + (long)kr1 * QKVW_ + ((kgg ^ (kr1 & 7)) << 3);
    const u16* vp0 = vb0 + (long)vr0 * T_ + ((vgg ^ (vr0 & 15)) << 3);
    const u16* vp1 = vb0 + (long)vr1 * T_ + ((vgg ^ (vr1 & 15)) << 3);
    u16* kl0 = Ks + tid * 8;
    u16* kl1 = Ks + (tid + 512) * 8;
    u16* vl0 = Vs + tid * 8;
    u16* vl1 = Vs + (tid + 512) * 8;

    bf16x8 kreg0, kreg1, vreg0, vreg1;
    auto stage_load = [&](int kt) {
        const long ko = (long)kt * 128 * QKVW_;   // K: rows advance with kt
        const int  vo = kt * 128;                 // V: cols advance with kt
        kreg0 = *(const bf16x8*)(kp0 + ko);
        kreg1 = *(const bf16x8*)(kp1 + ko);
        vreg0 = *(const bf16x8*)(vp0 + vo);
        vreg1 = *(const bf16x8*)(vp1 + vo);
    };
    auto stage_write = [&]() {
        *(bf16x8*)kl0 = kreg0;
        *(bf16x8*)kl1 = kreg1;
        *(bf16x8*)vl0 = vreg0;
        *(bf16x8*)vl1 = vreg1;
    };

    float m_[4], l_[4];
    f32x4 oacc[4];
#pragma unroll
    for (int i = 0; i < 4; i++) {
        m_[i] = -1e30f; l_[i] = 0.f;
        oacc[i] = (f32x4){0.f, 0.f, 0.f, 0.f};
    }

    stage_load(0);
    stage_write();
    __syncthreads();

    for (int kt = 0; kt < T_ / 128; kt++) {
        // Issue next tile's global loads NOW: latency hides under this
        // tile's QK^T + softmax + PV. (T14 async-STAGE split.)
        const bool pf = (kt + 1 < T_ / 128);
        if (pf) stage_load(kt + 1);

        // S = Q K^T  (16 q-rows x 128 k-cols per wave)
        f32x4 sacc[8];
#pragma unroll
        for (int ni = 0; ni < 8; ni++) sacc[ni] = (f32x4){0.f, 0.f, 0.f, 0.f};
        __builtin_amdgcn_s_setprio(1);
#pragma unroll
        for (int ks = 0; ks < 2; ks++) {
            bf16x8 qq = ks ? qf1 : qf0;
#pragma unroll
            for (int ni = 0; ni < 8; ni++) {
                bf16x8 kf = *(const bf16x8*)(Ks + (ni * 16 + fl) * 64 +
                                             (((ks * 4 + fq) ^ (fl & 7)) << 3));
                sacc[ni] = __builtin_amdgcn_mfma_f32_16x16x32_bf16(qq, kf, sacc[ni], 0, 0, 0);
            }
        }
        __builtin_amdgcn_s_setprio(0);

        float rmax[4];
#pragma unroll
        for (int r = 0; r < 4; r++) {
            float mm = sacc[0][r];
#pragma unroll
            for (int ni = 1; ni < 8; ni++) mm = fmaxf(mm, sacc[ni][r]);
            rmax[r] = mm * 0.125f;
        }
#pragma unroll
        for (int off = 1; off < 16; off <<= 1)
#pragma unroll
            for (int r = 0; r < 4; r++) rmax[r] = fmaxf(rmax[r], __shfl_xor(rmax[r], off));

        // T13 defer-max: only rescale when some row max grew by > 8;
        // otherwise keep old m_, P bounded by e^8 (f32 accum tolerates).
        bool grow = false;
        float nm[4];
#pragma unroll
        for (int r = 0; r < 4; r++) {
            nm[r] = fmaxf(m_[r], rmax[r]);
            grow = grow || (rmax[r] > m_[r] + 8.f);
        }
        if (__any(grow)) {
#pragma unroll
            for (int r = 0; r < 4; r++) {
                float a = __expf(m_[r] - nm[r]);
                m_[r] = nm[r];
                l_[r] *= a;
#pragma unroll
                for (int ni = 0; ni < 4; ni++) oacc[ni][r] *= a;
            }
        }

        float psum[4];
#pragma unroll
        for (int r = 0; r < 4; r++) psum[r] = 0.f;
        u16* pst = Ps[w];
#pragma unroll
        for (int ni = 0; ni < 8; ni++) {
            int colg = ni * 2 + (fl >> 3);
            int cl   = fl & 7;
#pragma unroll
            for (int r = 0; r < 4; r++) {
                int row = fq * 4 + r;
                float p = __expf(sacc[ni][r] * 0.125f - m_[r]);
                psum[r] += p;
                pst[row * 128 + ((colg ^ (row & 15)) << 3) + cl] = f2b(p);
            }
        }
#pragma unroll
        for (int off = 1; off < 16; off <<= 1)
#pragma unroll
            for (int r = 0; r < 4; r++) psum[r] += __shfl_xor(psum[r], off);
#pragma unroll
        for (int r = 0; r < 4; r++) l_[r] += psum[r];

        // O += P V   (K=128 over 4 ks steps)
        __builtin_amdgcn_s_setprio(1);
#pragma unroll
        for (int ks = 0; ks < 4; ks++) {
            bf16x8 pfr = *(const bf16x8*)(pst + fl * 128 +
                                          (((ks * 4 + fq) ^ fl) << 3));
#pragma unroll
            for (int ni = 0; ni < 4; ni++) {
                bf16x8 vf = *(const bf16x8*)(Vs + (ni * 16 + fl) * 128 +
                                             (((ks * 4 + fq) ^ fl) << 3));
                oacc[ni] = __builtin_amdgcn_mfma_f32_16x16x32_bf16(pfr, vf, oacc[ni], 0, 0, 0);
            }
        }
        __builtin_amdgcn_s_setprio(0);

        // All waves done reading Ks/Vs; write next tile (loads have been
        // in flight across the whole compute phase -> cheap vmcnt wait).
        __syncthreads();
        if (pf) {
            stage_write();
            __syncthreads();
        }
    }

#pragma unroll
    for (int r = 0; r < 4; r++) {
        float inv = 1.f / l_[r];
        u16* op = sab + (tok0 + w * 16 + fq * 4 + r) * D_ + h * 64 + fl;
#pragma unroll
        for (int ni = 0; ni < 4; ni++) op[ni * 16] = f2b(oacc[ni][r] * inv);
    }
}

// ---------------------------------------------------------------------------
// Residual add (3 inputs) + RMSNorm. BF=1 additionally writes bf16 copy.
// ---------------------------------------------------------------------------
template<int BF>
__global__ __launch_bounds__(256) void rmsnorm_res(const float* __restrict__ a,
                                                   const float* __restrict__ b,
                                                   const float* __restrict__ b2,
                                                   const float* __restrict__ w,
                                                   float* __restrict__ outf,
                                                   u16* __restrict__ outb) {
    const int s = blockIdx.x;
    const float* ar = a + (long)s * D_;
    const float* br = b + (long)s * D_;
    const float* cr2 = b2 + (long)s * D_;
    float y[4];
    float ss = 0.f;
#pragma unroll
    for (int kx = 0; kx < 4; kx++) {
        int j = threadIdx.x + kx * 256;
        y[kx] = ar[j] + br[j] + cr2[j];
        ss += y[kx] * y[kx];
    }
    __shared__ float red[4];
#pragma unroll
    for (int off = 32; off > 0; off >>= 1) ss += __shfl_down(ss, off);
    int lane = threadIdx.x & 63, wv = threadIdx.x >> 6;
    if (lane == 0) red[wv] = ss;
    __syncthreads();
    float tot = red[0] + red[1] + red[2] + red[3];
    float scl = rsqrtf(tot / (float)D_ + EPS_);
    float* orow = outf + (long)s * D_;
#pragma unroll
    for (int kx = 0; kx < 4; kx++) {
        int j = threadIdx.x + kx * 256;
        float v = y[kx] * scl * w[j];
        orow[j] = v;
        if (BF) outb[(long)s * D_ + j] = f2b(v);
    }
}

// ---------------------------------------------------------------------------
// Gating (fp32): one wave per token. Writes per-token top-2 (expert, weight).
// ---------------------------------------------------------------------------
__global__ __launch_bounds__(256) void gate_kernel(const float* __restrict__ x,
                                                   const float* __restrict__ Wg,
                                                   const float* __restrict__ We,
                                                   const float* __restrict__ gb,
                                                   const float* __restrict__ eb,
                                                   int* __restrict__ tok_e,
                                                   float* __restrict__ tok_w) {
    const int wave = threadIdx.x >> 6;
    const int lane = threadIdx.x & 63;
    const int s = blockIdx.x * 4 + wave;
    const float* xr = x + (long)s * D_;
    float g0 = 0.f, g1 = 0.f;
    float ee[8];
#pragma unroll
    for (int e = 0; e < 8; e++) ee[e] = 0.f;
    for (int j = lane; j < D_; j += 64) {
        float xv = xr[j];
        g0 += xv * Wg[j * 2 + 0];
        g1 += xv * Wg[j * 2 + 1];
#pragma unroll
        for (int e = 0; e < 8; e++) ee[e] += xv * We[j * 8 + e];
    }
#pragma unroll
    for (int off = 32; off > 0; off >>= 1) {
        g0 += __shfl_down(g0, off);
        g1 += __shfl_down(g1, off);
#pragma unroll
        for (int e = 0; e < 8; e++) ee[e] += __shfl_down(ee[e], off);
    }
    if (lane == 0) {
        g0 += gb[0];
        g1 += gb[1];
        int gidx = (g1 > g0) ? 1 : 0;
        float gm = fmaxf(g0, g1);
        float p0 = expf(g0 - gm), p1 = expf(g1 - gm);
        float gprob = (gidx ? p1 : p0) / (p0 + p1);
        int base = gidx * 4;
        float pe[4];
        float em = -1e30f;
#pragma unroll
        for (int i = 0; i < 4; i++) {
            pe[i] = ee[base + i] + eb[base + i];
            em = fmaxf(em, pe[i]);
        }
        float sum = 0.f;
#pragma unroll
        for (int i = 0; i < 4; i++) { pe[i] = expf(pe[i] - em); sum += pe[i]; }
        float inv = gprob / sum;
#pragma unroll
        for (int i = 0; i < 4; i++) pe[i] *= inv;
        int i1 = 0;
        for (int i = 1; i < 4; i++) if (pe[i] > pe[i1]) i1 = i;
        int i2 = -1;
        for (int i = 0; i < 4; i++) {
            if (i == i1) continue;
            if (i2 < 0 || pe[i] > pe[i2]) i2 = i;
        }
        tok_e[s * 2 + 0] = base + i1;
        tok_e[s * 2 + 1] = base + i2;
        tok_w[s * 2 + 0] = pe[i1];
        tok_w[s * 2 + 1] = pe[i2];
    }
}

// ---------------------------------------------------------------------------
// Single-block routing build: histogram + scan + scatter in LDS.
// ---------------------------------------------------------------------------
__global__ __launch_bounds__(256) void route_build(const int* __restrict__ tok_e,
                                                   const float* __restrict__ tok_w,
                                                   int* __restrict__ counts_g,
                                                   int* __restrict__ bases_g,
                                                   int* __restrict__ list,
                                                   float* __restrict__ wlist) {
    __shared__ int cnt[E_], bas[E_], cur[E_];
    const int tid = threadIdx.x;
    if (tid < E_) cnt[tid] = 0;
    __syncthreads();
    for (int i = tid; i < 2 * S_; i += 256) atomicAdd(&cnt[tok_e[i]], 1);
    __syncthreads();
    if (tid == 0) {
        int acc = 0;
        for (int e = 0; e < E_; e++) { bas[e] = acc; cur[e] = acc; acc += cnt[e]; }
    }
    __syncthreads();
    if (tid < E_) { counts_g[tid] = cnt[tid]; bases_g[tid] = bas[tid]; }
    for (int i = tid; i < 2 * S_; i += 256) {
        int e = tok_e[i];
        int p = atomicAdd(&cur[e], 1);
        list[p] = i >> 1;
        wlist[p] = tok_w[i];
    }
}

// ---------------------------------------------------------------------------
extern "C" void kernel_launch(void* const* d_in, const int* in_sizes, int n_in,
                              void* d_out, int out_size, void* d_ws, size_t ws_size,
                              hipStream_t stream) {
    const float* src  = (const float*)d_in[0];
    const float* Wq   = (const float*)d_in[1];
    const float* Wk_c = (const float*)d_in[2];
    const float* Wv_c = (const float*)d_in[3];
    const float* Wk   = (const float*)d_in[4];
    const float* Wv   = (const float*)d_in[5];
    const float* Wo   = (const float*)d_in[6];
    const float* Wsin = (const float*)d_in[7];
    const float* Wsout= (const float*)d_in[8];
    const float* W1   = (const float*)d_in[9];
    const float* W2   = (const float*)d_in[10];
    const float* Wg   = (const float*)d_in[11];
    const float* We   = (const float*)d_in[12];
    const float* gb   = (const float*)d_in[13];
    const float* eb   = (const float*)d_in[14];
    const float* n1w  = (const float*)d_in[15];
    const float* n2w  = (const float*)d_in[16];
    float* out = (float*)d_out;

    const size_t MB = 1u << 20;
    char* w8 = (char*)d_ws;
    // Layout (MiB offsets). Lifetimes:
    u16*  qkv   = (u16*)(w8);              // 0..24; dead after attn
    u16*  vtg   = (u16*)(w8 + 24 * MB);    // 24..32; dead after attn
    float* oproj0 = (float*)(w8);          // 0..16 (after attn; dead after rmsnorm1)
    float* oproj1 = (float*)(w8 + 16 * MB);// 16..32 (same)
    u16*  w2t   = (u16*)(w8);              // 0..32 (after rmsnorm1)
    u16*  WkcB  = (u16*)(w8 + 24 * MB);    // early temps (dead before vt_conv)
    u16*  WvcB  = (u16*)(w8 + 24 * MB + 512 * 1024);
    u16*  WkTs  = (u16*)(w8 + 25 * MB);
    u16*  WvTs  = (u16*)(w8 + 25 * MB + 512 * 1024);
    u16*  sab   = (u16*)(w8 + 32 * MB);    // 32..40; dead after Wo gemm
    float* tokw = (float*)(w8 + 32 * MB);  // gating arrays overlay dead sab
    float* wlist = tokw + 2 * S_;
    int* toke   = (int*)(wlist + 2 * S_);
    int* list   = toke + 2 * S_;
    int* counts = list + 2 * S_;
    int* bases  = counts + E_;
    float* x1   = (float*)(w8 + 40 * MB);  // 40..56
    float* ffn0 = (float*)(w8 + 56 * MB);  // 56..72
    u16*  x1b   = (u16*)(w8 + 72 * MB);    // 72..80 (dead after FFN-in gemm)
    u16*  hbuf  = (u16*)(w8 + 80 * MB);    // 80..96 (shared-FFN h)
    u16*  srcb  = (u16*)(w8 + 96 * MB);    // 96..104 (early; dead after QKV gemm)
    float2* rtab= (float2*)(w8 + 104 * MB);// 104..104.5 (dead after rope_apply)
    u16*  hbuf2 = (u16*)(w8 + 96 * MB);    // 96..112 (routed h; after srcb/rtab dead)
    u16*  WqkvT = (u16*)(w8 + 112 * MB);   // 112..118 (early)
    u16*  WsoutT= (u16*)(w8 + 112 * MB);   // 112..116 (after WqkvT dead)
    u16*  WoT   = (u16*)(w8 + 118 * MB);   // 118..120
    u16*  WsinT = (u16*)(w8 + 120 * MB);   // 120..128 (dead after FFN-in)
    u16*  W1T   = (u16*)(w8 + 128 * MB);   // 128..136 (dead after FFN-in)
    float* ffn1 = (float*)(w8 + 120 * MB); // 120..136 (overlays WsinT/W1T, late)

    dim3 blk(256);

    // --- build fused QKV weight (3072 x 1024 bf16, Bt layout) ---
    conv_t<<<dim3(32, 32), blk, 0, stream>>>(Wq, WqkvT, 1024, 1024, 0, 0, 0);
    convert_bf16<<<dim3(D_ * DC_ / 4 / 256), blk, 0, stream>>>(Wk_c, WkcB, D_ * DC_ / 4);
    convert_bf16<<<dim3(D_ * DC_ / 4 / 256), blk, 0, stream>>>(Wv_c, WvcB, D_ * DC_ / 4);
    conv_t<<<dim3(32, 8), blk, 0, stream>>>(Wk, WkTs, 256, 1024, 0, 0, 0);
    conv_t<<<dim3(32, 8), blk, 0, stream>>>(Wv, WvTs, 256, 1024, 0, 0, 0);
    gemm_bf16<2><<<dim3(8, 8), blk, 0, stream>>>(WkcB, WkTs, WqkvT + 1024 * 1024, 1024, 256, 1024, nullptr);
    gemm_bf16<2><<<dim3(8, 8), blk, 0, stream>>>(WvcB, WvTs, WqkvT + 2048 * 1024, 1024, 256, 1024, nullptr);

    convert_bf16<<<dim3(S_ * D_ / 4 / 256), blk, 0, stream>>>(src, srcb, S_ * D_ / 4);

    // Fused QKV projection: (S,1024) @ (1024,3072) -> qkv (S,3072)
    gemm_bf16<1><<<dim3(24, 32), blk, 0, stream>>>(srcb, WqkvT, qkv, QKVW_, 1024, QKVW_, nullptr);

    // other weight conversions (WqkvT dead; WsoutT overlays it)
    conv_t<<<dim3(32, 32), blk, 0, stream>>>(Wo, WoT, 1024, 1024, 0, 0, 0);
    conv_t<<<dim3(128, 32), blk, 0, stream>>>(Wsin, WsinT, 1024, 4096, 0, 0, 1);
    conv_t<<<dim3(32, 64), blk, 0, stream>>>(Wsout, WsoutT, 2048, 1024, 0, 0, 0);
    conv_t<<<dim3(128, 32), blk, 0, stream>>>(W1, W1T, 1024, 4096, 0, 0, 1);

    // RoPE (table + vectorized apply)
    rope_table<<<dim3(T_ * 32 / 256), blk, 0, stream>>>(rtab);
    rope_apply<<<dim3(S_ * 2048 / 8 / 256), blk, 0, stream>>>(qkv, rtab);

    vt_conv<<<dim3(T_ / 32, 2, B_ * H_), blk, 0, stream>>>(qkv, vtg);
    attn_kernel<<<dim3(T_ / 128, B_ * H_), dim3(512), 0, stream>>>(qkv, vtg, sab);

    // Wo projection, split-K=2 plain stores into two buffers
    gemm_bf16<5><<<dim3(8, 32, 2), blk, 0, stream>>>(sab, WoT, oproj0, 1024, 1024, 1024, oproj1);
    rmsnorm_res<1><<<dim3(S_), blk, 0, stream>>>(src, oproj0, oproj1, n1w, x1, x1b);

    // Merged FFN-in (shared + routed W1) with fused swiglu -> hbuf, hbuf2
    gemm_bf16<3><<<dim3(64, 32), blk, 0, stream>>>(x1b, WsinT, hbuf, 8192, 1024, 2048, nullptr);

    // Shared FFN-out, split-K=2 plain stores -> ffn0, ffn1
    gemm_bf16<5><<<dim3(8, 32, 2), blk, 0, stream>>>(hbuf, WsoutT, ffn0, 1024, 2048, 1024, ffn1);

    // Gating + routing lists
    gate_kernel<<<dim3(S_ / 4), blk, 0, stream>>>(x1, Wg, We, gb, eb, toke, tokw);
    route_build<<<dim3(1), blk, 0, stream>>>(toke, tokw, counts, bases, list, wlist);

    // Routed experts: W2 transpose, gathered GEMM atomicAdd onto ffn0
    conv_t<<<dim3(32, 64, 8), blk, 0, stream>>>(W2, w2t, 2048, 1024,
                                                (long)HID_ * D_, (long)D_ * HID_, 0);
    routed_gemm<<<dim3(8, E_ * 32), blk, 0, stream>>>(hbuf2, w2t, list, wlist,
                                                      bases, counts, ffn0);

    rmsnorm_res<0><<<dim3(S_), blk, 0, stream>>>(x1, ffn0, ffn1, n2w, out, (u16*)nullptr);
}

// Round 3
// 671.463 us; speedup vs baseline: 1.1338x; 1.0344x over previous
//
#include <hip/hip_runtime.h>
#include <math.h>

#define D_    1024
#define H_    16
#define DH_   64
#define DC_   256
#define HID_  2048
#define E_    8
#define B_    2
#define T_    2048
#define S_    4096
#define EPS_  1e-6f
#define QKVW_ 3072   // fused qkv row width

typedef unsigned short u16;
typedef short bf16x8 __attribute__((ext_vector_type(8)));
typedef float f32x4 __attribute__((ext_vector_type(4)));

__device__ __forceinline__ float b2f(u16 u) {
    return __uint_as_float(((unsigned int)u) << 16);
}
__device__ __forceinline__ u16 f2b(float f) {
    unsigned int u = __float_as_uint(f);
    u += 0x7FFF + ((u >> 16) & 1);
    return (u16)(u >> 16);
}
__device__ __forceinline__ void g2l16(const u16* g, u16* l) {
    __builtin_amdgcn_global_load_lds(
        (const __attribute__((address_space(1))) void*)g,
        (__attribute__((address_space(3))) void*)l, 16, 0, 0);
}

// ---------------------------------------------------------------------------
// Transpose + fp32->bf16: in (K,N) fp32 -> out (N,K) bf16.
// perm=1: swiglu column interleave for fused epilogue.
// ---------------------------------------------------------------------------
__global__ __launch_bounds__(256) void conv_t(const float* __restrict__ in,
                                              u16* __restrict__ out,
                                              int K, int N,
                                              long inZ, long outZ, int perm) {
    in  += (long)blockIdx.z * inZ;
    out += (long)blockIdx.z * outZ;
    __shared__ float t[32][33];
    const int n0 = blockIdx.x * 32, k0 = blockIdx.y * 32;
    int src_n0 = n0;
    if (perm) {
        int t64 = n0 >> 6;
        src_n0 = ((n0 & 63) == 0) ? t64 * 32 : (N / 2 + t64 * 32);
    }
    const int tx = threadIdx.x & 31, ty = threadIdx.x >> 5;
#pragma unroll
    for (int i = 0; i < 4; i++)
        t[ty + 8 * i][tx] = in[(long)(k0 + ty + 8 * i) * N + src_n0 + tx];
    __syncthreads();
#pragma unroll
    for (int i = 0; i < 4; i++)
        out[(long)(n0 + ty + 8 * i) * K + k0 + tx] = f2b(t[tx][ty + 8 * i]);
}

// bf16 transpose V rows of fused qkv (stride QKVW_) per-head -> Vt [bh][64][T]
__global__ __launch_bounds__(256) void vt_conv(const u16* __restrict__ qkv,
                                               u16* __restrict__ vt) {
    __shared__ u16 t[32][34];
    const int bh = blockIdx.z;
    const int b = bh >> 4, h = bh & 15;
    const int t0 = blockIdx.x * 32, d0 = blockIdx.y * 32;
    const int tx = threadIdx.x & 31, ty = threadIdx.x >> 5;
#pragma unroll
    for (int i = 0; i < 4; i++)
        t[ty + 8 * i][tx] =
            qkv[((long)b * T_ + t0 + ty + 8 * i) * QKVW_ + 2048 + h * 64 + d0 + tx];
    __syncthreads();
#pragma unroll
    for (int i = 0; i < 4; i++)
        vt[((long)bh * 64 + d0 + ty + 8 * i) * T_ + t0 + tx] = t[tx][ty + 8 * i];
}

// Elementwise fp32 -> bf16
__global__ __launch_bounds__(256) void convert_bf16(const float* __restrict__ in,
                                                    u16* __restrict__ out, int n4) {
    int i = blockIdx.x * 256 + threadIdx.x;
    if (i >= n4) return;
    float4 f = ((const float4*)in)[i];
    ushort4 o;
    o.x = f2b(f.x); o.y = f2b(f.y); o.z = f2b(f.z); o.w = f2b(f.w);
    ((ushort4*)out)[i] = o;
}

// ---------------------------------------------------------------------------
// bf16 MFMA GEMM: C(M,N) = A(M,K) @ Bt(N,K)^T. 128x128, BK=32, 4 waves.
// OUTMODE 1: bf16 store | 2: bf16 transposed store (ldo=M)
// OUTMODE 3: swiglu epilogue, dual output: blockIdx.x>=32 -> Cp + S_*HID_
// OUTMODE 5: split-K (gridDim.z=2), fp32 plain store; z=0 -> Cp, z=1 -> Cp2
// ---------------------------------------------------------------------------
template<int OUTMODE>
__global__ __launch_bounds__(256) void gemm_bf16(const u16* __restrict__ A,
                                                 const u16* __restrict__ Bt,
                                                 void* __restrict__ Cp,
                                                 int N, int K, int ldo,
                                                 void* __restrict__ Cp2) {
    __shared__ u16 As[128 * 32];
    __shared__ u16 Bs[128 * 32];
    const int tid  = threadIdx.x;
    const int lane = tid & 63;
    const int wv   = tid >> 6;
    const int wm   = wv >> 1, wn = wv & 1;
    const long row0 = (long)blockIdx.y * 128;
    const long col0 = (long)blockIdx.x * 128;
    const int Klocal = K / gridDim.z;
    const long koff  = (long)blockIdx.z * Klocal;

    f32x4 acc[4][4];
#pragma unroll
    for (int i = 0; i < 4; i++)
#pragma unroll
        for (int j = 0; j < 4; j++) acc[i][j] = (f32x4){0.f, 0.f, 0.f, 0.f};

    const int sr = tid >> 2;
    const int sc = (tid & 3) << 3;
    const u16* Ag  = A  + (row0 + sr) * (long)K + koff + sc;
    const u16* Ag2 = Ag + 64 * (long)K;
    const u16* Bg  = Bt + (col0 + sr) * (long)K + koff + sc;
    const u16* Bg2 = Bg + 64 * (long)K;
    u16* lA  = As + tid * 8;
    u16* lA2 = As + 2048 + tid * 8;
    u16* lB  = Bs + tid * 8;
    u16* lB2 = Bs + 2048 + tid * 8;

    const int fl = lane & 15;
    const int fk = (lane >> 4) << 3;
    const u16* ArA = As + (wm * 64 + fl) * 32 + fk;
    const u16* BrB = Bs + (wn * 64 + fl) * 32 + fk;

    for (int k0 = 0; k0 < Klocal; k0 += 32) {
        __syncthreads();
        g2l16(Ag + k0, lA);
        g2l16(Ag2 + k0, lA2);
        g2l16(Bg + k0, lB);
        g2l16(Bg2 + k0, lB2);
        __syncthreads();
        bf16x8 af[4], bfr[4];
#pragma unroll
        for (int mi = 0; mi < 4; mi++) af[mi]  = *(const bf16x8*)(ArA + mi * 512);
#pragma unroll
        for (int ni = 0; ni < 4; ni++) bfr[ni] = *(const bf16x8*)(BrB + ni * 512);
#pragma unroll
        for (int mi = 0; mi < 4; mi++)
#pragma unroll
            for (int ni = 0; ni < 4; ni++)
                acc[mi][ni] = __builtin_amdgcn_mfma_f32_16x16x32_bf16(
                    af[mi], bfr[ni], acc[mi][ni], 0, 0, 0);
    }

    const int cr = (lane >> 4) << 2;
    const int cc = lane & 15;
#pragma unroll
    for (int mi = 0; mi < 4; mi++) {
#pragma unroll
        for (int r = 0; r < 4; r++) {
            long grow = row0 + wm * 64 + mi * 16 + cr + r;
            if (OUTMODE == 3) {
                u16* outb = (u16*)Cp + (long)(blockIdx.x >> 5) * S_ * HID_;
                u16* hrow = outb + grow * ldo + (blockIdx.x & 31) * 64 + wn * 32;
#pragma unroll
                for (int ni = 0; ni < 2; ni++) {
                    float a = acc[mi][ni][r], b = acc[mi][ni + 2][r];
                    float sig = 1.f / (1.f + __expf(-a));
                    hrow[ni * 16 + cc] = f2b(a * sig * b);
                }
            } else {
#pragma unroll
                for (int ni = 0; ni < 4; ni++) {
                    long gcol = col0 + wn * 64 + ni * 16 + cc;
                    float v = acc[mi][ni][r];
                    if (OUTMODE == 1)      ((u16*)Cp)[grow * ldo + gcol] = f2b(v);
                    else if (OUTMODE == 2) ((u16*)Cp)[gcol * ldo + grow] = f2b(v);
                    else {
                        float* basep = (float*)(blockIdx.z ? Cp2 : Cp);
                        basep[grow * ldo + gcol] = v;
                    }
                }
            }
        }
    }
}

// ---------------------------------------------------------------------------
// Routed-expert bf16 MFMA GEMM (gathered rows, scaled atomicAdd epilogue)
// ---------------------------------------------------------------------------
__global__ __launch_bounds__(256) void routed_gemm(const u16* __restrict__ Hh,
                                                   const u16* __restrict__ W2T,
                                                   const int* __restrict__ list,
                                                   const float* __restrict__ wlist,
                                                   const int* __restrict__ bases,
                                                   const int* __restrict__ counts,
                                                   float* __restrict__ Cout) {
    const int e    = blockIdx.y >> 5;
    const int tile = blockIdx.y & 31;
    const int cnt  = counts[e];
    if (tile * 128 >= cnt) return;
    const int base = bases[e];

    __shared__ u16 As[128 * 32];
    __shared__ u16 Bs[128 * 32];
    __shared__ int   toks[128];
    __shared__ float wrow[128];

    const int tid = threadIdx.x;
    if (tid < 128) {
        int ridx = tile * 128 + tid;
        if (ridx < cnt) { toks[tid] = list[base + ridx]; wrow[tid] = wlist[base + ridx]; }
        else            { toks[tid] = -1;                wrow[tid] = 0.f; }
    }
    __syncthreads();

    const int lane = tid & 63;
    const int wv   = tid >> 6;
    const int wm   = wv >> 1, wn = wv & 1;
    const long col0 = (long)blockIdx.x * 128;

    f32x4 acc[4][4];
#pragma unroll
    for (int i = 0; i < 4; i++)
#pragma unroll
        for (int j = 0; j < 4; j++) acc[i][j] = (f32x4){0.f, 0.f, 0.f, 0.f};

    const int sr = tid >> 2;
    const int sc = (tid & 3) << 3;
    const int t1 = toks[sr], t2 = toks[sr + 64];
    const u16* Ag  = Hh + (long)(t1 < 0 ? 0 : t1) * HID_ + sc;
    const u16* Ag2 = Hh + (long)(t2 < 0 ? 0 : t2) * HID_ + sc;
    const u16* Bg  = W2T + (long)e * D_ * HID_ + (col0 + sr) * (long)HID_ + sc;
    const u16* Bg2 = Bg + 64 * (long)HID_;
    u16* lA  = As + tid * 8;
    u16* lA2 = As + 2048 + tid * 8;
    u16* lB  = Bs + tid * 8;
    u16* lB2 = Bs + 2048 + tid * 8;

    const int fl = lane & 15;
    const int fk = (lane >> 4) << 3;
    const u16* ArA = As + (wm * 64 + fl) * 32 + fk;
    const u16* BrB = Bs + (wn * 64 + fl) * 32 + fk;

    for (int k0 = 0; k0 < HID_; k0 += 32) {
        __syncthreads();
        g2l16(Ag + k0, lA);
        g2l16(Ag2 + k0, lA2);
        g2l16(Bg + k0, lB);
        g2l16(Bg2 + k0, lB2);
        __syncthreads();
        bf16x8 af[4], bfr[4];
#pragma unroll
        for (int mi = 0; mi < 4; mi++) af[mi]  = *(const bf16x8*)(ArA + mi * 512);
#pragma unroll
        for (int ni = 0; ni < 4; ni++) bfr[ni] = *(const bf16x8*)(BrB + ni * 512);
#pragma unroll
        for (int mi = 0; mi < 4; mi++)
#pragma unroll
            for (int ni = 0; ni < 4; ni++)
                acc[mi][ni] = __builtin_amdgcn_mfma_f32_16x16x32_bf16(
                    af[mi], bfr[ni], acc[mi][ni], 0, 0, 0);
    }

    const int cr = (lane >> 4) << 2;
    const int cc = lane & 15;
#pragma unroll
    for (int mi = 0; mi < 4; mi++) {
#pragma unroll
        for (int r = 0; r < 4; r++) {
            int rr = wm * 64 + mi * 16 + cr + r;
            int tk = toks[rr];
            if (tk < 0) continue;
            float wvw = wrow[rr];
            float* crow = Cout + (long)tk * D_ + col0 + wn * 64;
#pragma unroll
            for (int ni = 0; ni < 4; ni++)
                atomicAdd(crow + ni * 16 + cc, acc[mi][ni][r] * wvw);
        }
    }
}

// ---------------------------------------------------------------------------
// RoPE: sincos table (T_ x 32) then vectorized apply on q,k cols of qkv.
// ---------------------------------------------------------------------------
__global__ __launch_bounds__(256) void rope_table(float2* __restrict__ tab) {
    int idx = blockIdx.x * 256 + threadIdx.x;     // 65536
    int t = idx >> 5, i = idx & 31;
    float ang = (float)t * powf(10000.f, -(float)i / 32.f);
    float sn, cs;
    sincosf(ang, &sn, &cs);
    tab[idx] = make_float2(sn, cs);
}

__global__ __launch_bounds__(256) void rope_apply(u16* __restrict__ qkv,
                                                  const float2* __restrict__ tab) {
    long p = (long)blockIdx.x * 256 + threadIdx.x;   // S_*2048/8 groups
    int s  = (int)(p >> 8);
    int c8 = (int)(p & 255) << 3;
    int t  = s & (T_ - 1);
    const float2* tp = tab + t * 32 + ((c8 & 63) >> 1);
    u16* px = qkv + (long)s * QKVW_ + c8;
    bf16x8 v = *(const bf16x8*)px;
    bf16x8 o;
#pragma unroll
    for (int j = 0; j < 4; j++) {
        float x1 = b2f((u16)v[2 * j]), x2 = b2f((u16)v[2 * j + 1]);
        float2 sc = tp[j];
        o[2 * j]     = (short)f2b(x1 * sc.y - x2 * sc.x);
        o[2 * j + 1] = (short)f2b(x1 * sc.x + x2 * sc.y);
    }
    *(bf16x8*)px = o;
}

// ---------------------------------------------------------------------------
// MFMA flash attention, 128-key x 128-query tiles. grid (T/128, B*H),
// 512 thr = 8 waves x 16 q-rows.
// v4 = v3 with the launch-bounds occupancy hint REMOVED: the ",4" hint made
//     the allocator cap at 64 VGPR and spill ~270MB of scratch per dispatch
//     (WRITE_SIZE 284MB, rocprof r2). Plain (512) lets the kernel keep its
//     ~110 live VGPRs in registers. T14 async-STAGE split + XCD swizzle +
//     setprio + defer-max retained. LDS: Ks 16KB + Vs 16KB + Ps 32KB = 64KB.
// ---------------------------------------------------------------------------
__global__ __launch_bounds__(512) void attn_kernel(const u16* __restrict__ qkv,
                                                   const u16* __restrict__ vtg,
                                                   u16* __restrict__ sab) {
    __shared__ u16 Ks[128 * 64];
    __shared__ u16 Vs[64 * 128];
    __shared__ u16 Ps[8][16 * 128];
    const int tid  = threadIdx.x;
    const int lane = tid & 63;
    const int w    = tid >> 6;          // 0..7
    // XCD-aware bijective swizzle: flat 0..511; xcd = flat&7 owns 64
    // consecutive virtual ids = 4 bh * 16 qtiles (K/V 2MB < 4MB L2).
    const int flat = blockIdx.x + (blockIdx.y << 4);
    const int virt = ((flat & 7) << 6) | (flat >> 3);
    const int qt = virt & 15;
    const int bh = virt >> 4;
    const int b  = bh >> 4, h = bh & 15;
    const long tok0 = (long)b * T_ + qt * 128;
    const int fl = lane & 15;
    const int fq = lane >> 4;

    bf16x8 qf0, qf1;
    {
        const u16* qp = qkv + (tok0 + w * 16 + fl) * QKVW_ + h * 64 + fq * 8;
        qf0 = *(const bf16x8*)qp;
        qf1 = *(const bf16x8*)(qp + 32);
    }

    const u16* kb0 = qkv + ((long)b * T_) * QKVW_ + 1024 + h * 64;
    const u16* vb0 = vtg + ((long)bh * 64) * T_;

    // ---- T14 register staging: per-thread 4x16B, addressing identical to v1
    // K slots: i = tid / tid+512; row = i>>3 (128 key rows), grp = i&7,
    //          source column XOR-swizzled so LDS stays linear.
    // V slots: i = tid / tid+512; row = i>>4 (64 d rows), grp = i&15.
    const int kr0 = tid >> 3,         kgg = tid & 7;
    const int kr1 = (tid + 512) >> 3;
    const int vr0 = tid >> 4,         vgg = tid & 15;
    const int vr1 = (tid + 512) >> 4;
    const u16* kp0 = kb0 + (long)kr0 * QKVW_ + ((kgg ^ (kr0 & 7)) << 3);
    const u16* kp1 = kb0 + (long)kr1 * QKVW_ + ((kgg ^ (kr1 & 7)) << 3);
    const u16* vp0 = vb0 + (long)vr0 * T_ + ((vgg ^ (vr0 & 15)) << 3);
    const u16* vp1 = vb0 + (long)vr1 * T_ + ((vgg ^ (vr1 & 15)) << 3);
    u16* kl0 = Ks + tid * 8;
    u16* kl1 = Ks + (tid + 512) * 8;
    u16* vl0 = Vs + tid * 8;
    u16* vl1 = Vs + (tid + 512) * 8;

    bf16x8 kreg0, kreg1, vreg0, vreg1;
    auto stage_load = [&](int kt) {
        const long ko = (long)kt * 128 * QKVW_;   // K: rows advance with kt
        const int  vo = kt * 128;                 // V: cols advance with kt
        kreg0 = *(const bf16x8*)(kp0 + ko);
        kreg1 = *(const bf16x8*)(kp1 + ko);
        vreg0 = *(const bf16x8*)(vp0 + vo);
        vreg1 = *(const bf16x8*)(vp1 + vo);
    };
    auto stage_write = [&]() {
        *(bf16x8*)kl0 = kreg0;
        *(bf16x8*)kl1 = kreg1;
        *(bf16x8*)vl0 = vreg0;
        *(bf16x8*)vl1 = vreg1;
    };

    float m_[4], l_[4];
    f32x4 oacc[4];
#pragma unroll
    for (int i = 0; i < 4; i++) {
        m_[i] = -1e30f; l_[i] = 0.f;
        oacc[i] = (f32x4){0.f, 0.f, 0.f, 0.f};
    }

    stage_load(0);
    stage_write();
    __syncthreads();

    for (int kt = 0; kt < T_ / 128; kt++) {
        // Issue next tile's global loads NOW: latency hides under this
        // tile's QK^T + softmax + PV. (T14 async-STAGE split.)
        const bool pf = (kt + 1 < T_ / 128);
        if (pf) stage_load(kt + 1);

        // S = Q K^T  (16 q-rows x 128 k-cols per wave)
        f32x4 sacc[8];
#pragma unroll
        for (int ni = 0; ni < 8; ni++) sacc[ni] = (f32x4){0.f, 0.f, 0.f, 0.f};
        __builtin_amdgcn_s_setprio(1);
#pragma unroll
        for (int ks = 0; ks < 2; ks++) {
            bf16x8 qq = ks ? qf1 : qf0;
#pragma unroll
            for (int ni = 0; ni < 8; ni++) {
                bf16x8 kf = *(const bf16x8*)(Ks + (ni * 16 + fl) * 64 +
                                             (((ks * 4 + fq) ^ (fl & 7)) << 3));
                sacc[ni] = __builtin_amdgcn_mfma_f32_16x16x32_bf16(qq, kf, sacc[ni], 0, 0, 0);
            }
        }
        __builtin_amdgcn_s_setprio(0);

        float rmax[4];
#pragma unroll
        for (int r = 0; r < 4; r++) {
            float mm = sacc[0][r];
#pragma unroll
            for (int ni = 1; ni < 8; ni++) mm = fmaxf(mm, sacc[ni][r]);
            rmax[r] = mm * 0.125f;
        }
#pragma unroll
        for (int off = 1; off < 16; off <<= 1)
#pragma unroll
            for (int r = 0; r < 4; r++) rmax[r] = fmaxf(rmax[r], __shfl_xor(rmax[r], off));

        // T13 defer-max: only rescale when some row max grew by > 8;
        // otherwise keep old m_, P bounded by e^8 (f32 accum tolerates).
        bool grow = false;
        float nm[4];
#pragma unroll
        for (int r = 0; r < 4; r++) {
            nm[r] = fmaxf(m_[r], rmax[r]);
            grow = grow || (rmax[r] > m_[r] + 8.f);
        }
        if (__any(grow)) {
#pragma unroll
            for (int r = 0; r < 4; r++) {
                float a = __expf(m_[r] - nm[r]);
                m_[r] = nm[r];
                l_[r] *= a;
#pragma unroll
                for (int ni = 0; ni < 4; ni++) oacc[ni][r] *= a;
            }
        }

        float psum[4];
#pragma unroll
        for (int r = 0; r < 4; r++) psum[r] = 0.f;
        u16* pst = Ps[w];
#pragma unroll
        for (int ni = 0; ni < 8; ni++) {
            int colg = ni * 2 + (fl >> 3);
            int cl   = fl & 7;
#pragma unroll
            for (int r = 0; r < 4; r++) {
                int row = fq * 4 + r;
                float p = __expf(sacc[ni][r] * 0.125f - m_[r]);
                psum[r] += p;
                pst[row * 128 + ((colg ^ (row & 15)) << 3) + cl] = f2b(p);
            }
        }
#pragma unroll
        for (int off = 1; off < 16; off <<= 1)
#pragma unroll
            for (int r = 0; r < 4; r++) psum[r] += __shfl_xor(psum[r], off);
#pragma unroll
        for (int r = 0; r < 4; r++) l_[r] += psum[r];

        // O += P V   (K=128 over 4 ks steps)
        __builtin_amdgcn_s_setprio(1);
#pragma unroll
        for (int ks = 0; ks < 4; ks++) {
            bf16x8 pfr = *(const bf16x8*)(pst + fl * 128 +
                                          (((ks * 4 + fq) ^ fl) << 3));
#pragma unroll
            for (int ni = 0; ni < 4; ni++) {
                bf16x8 vf = *(const bf16x8*)(Vs + (ni * 16 + fl) * 128 +
                                             (((ks * 4 + fq) ^ fl) << 3));
                oacc[ni] = __builtin_amdgcn_mfma_f32_16x16x32_bf16(pfr, vf, oacc[ni], 0, 0, 0);
            }
        }
        __builtin_amdgcn_s_setprio(0);

        // All waves done reading Ks/Vs; write next tile (loads have been
        // in flight across the whole compute phase -> cheap vmcnt wait).
        __syncthreads();
        if (pf) {
            stage_write();
            __syncthreads();
        }
    }

#pragma unroll
    for (int r = 0; r < 4; r++) {
        float inv = 1.f / l_[r];
        u16* op = sab + (tok0 + w * 16 + fq * 4 + r) * D_ + h * 64 + fl;
#pragma unroll
        for (int ni = 0; ni < 4; ni++) op[ni * 16] = f2b(oacc[ni][r] * inv);
    }
}

// ---------------------------------------------------------------------------
// Residual add (3 inputs) + RMSNorm. BF=1 additionally writes bf16 copy.
// ---------------------------------------------------------------------------
template<int BF>
__global__ __launch_bounds__(256) void rmsnorm_res(const float* __restrict__ a,
                                                   const float* __restrict__ b,
                                                   const float* __restrict__ b2,
                                                   const float* __restrict__ w,
                                                   float* __restrict__ outf,
                                                   u16* __restrict__ outb) {
    const int s = blockIdx.x;
    const float* ar = a + (long)s * D_;
    const float* br = b + (long)s * D_;
    const float* cr2 = b2 + (long)s * D_;
    float y[4];
    float ss = 0.f;
#pragma unroll
    for (int kx = 0; kx < 4; kx++) {
        int j = threadIdx.x + kx * 256;
        y[kx] = ar[j] + br[j] + cr2[j];
        ss += y[kx] * y[kx];
    }
    __shared__ float red[4];
#pragma unroll
    for (int off = 32; off > 0; off >>= 1) ss += __shfl_down(ss, off);
    int lane = threadIdx.x & 63, wv = threadIdx.x >> 6;
    if (lane == 0) red[wv] = ss;
    __syncthreads();
    float tot = red[0] + red[1] + red[2] + red[3];
    float scl = rsqrtf(tot / (float)D_ + EPS_);
    float* orow = outf + (long)s * D_;
#pragma unroll
    for (int kx = 0; kx < 4; kx++) {
        int j = threadIdx.x + kx * 256;
        float v = y[kx] * scl * w[j];
        orow[j] = v;
        if (BF) outb[(long)s * D_ + j] = f2b(v);
    }
}

// ---------------------------------------------------------------------------
// Gating (fp32): one wave per token. Writes per-token top-2 (expert, weight).
// ---------------------------------------------------------------------------
__global__ __launch_bounds__(256) void gate_kernel(const float* __restrict__ x,
                                                   const float* __restrict__ Wg,
                                                   const float* __restrict__ We,
                                                   const float* __restrict__ gb,
                                                   const float* __restrict__ eb,
                                                   int* __restrict__ tok_e,
                                                   float* __restrict__ tok_w) {
    const int wave = threadIdx.x >> 6;
    const int lane = threadIdx.x & 63;
    const int s = blockIdx.x * 4 + wave;
    const float* xr = x + (long)s * D_;
    float g0 = 0.f, g1 = 0.f;
    float ee[8];
#pragma unroll
    for (int e = 0; e < 8; e++) ee[e] = 0.f;
    for (int j = lane; j < D_; j += 64) {
        float xv = xr[j];
        g0 += xv * Wg[j * 2 + 0];
        g1 += xv * Wg[j * 2 + 1];
#pragma unroll
        for (int e = 0; e < 8; e++) ee[e] += xv * We[j * 8 + e];
    }
#pragma unroll
    for (int off = 32; off > 0; off >>= 1) {
        g0 += __shfl_down(g0, off);
        g1 += __shfl_down(g1, off);
#pragma unroll
        for (int e = 0; e < 8; e++) ee[e] += __shfl_down(ee[e], off);
    }
    if (lane == 0) {
        g0 += gb[0];
        g1 += gb[1];
        int gidx = (g1 > g0) ? 1 : 0;
        float gm = fmaxf(g0, g1);
        float p0 = expf(g0 - gm), p1 = expf(g1 - gm);
        float gprob = (gidx ? p1 : p0) / (p0 + p1);
        int base = gidx * 4;
        float pe[4];
        float em = -1e30f;
#pragma unroll
        for (int i = 0; i < 4; i++) {
            pe[i] = ee[base + i] + eb[base + i];
            em = fmaxf(em, pe[i]);
        }
        float sum = 0.f;
#pragma unroll
        for (int i = 0; i < 4; i++) { pe[i] = expf(pe[i] - em); sum += pe[i]; }
        float inv = gprob / sum;
#pragma unroll
        for (int i = 0; i < 4; i++) pe[i] *= inv;
        int i1 = 0;
        for (int i = 1; i < 4; i++) if (pe[i] > pe[i1]) i1 = i;
        int i2 = -1;
        for (int i = 0; i < 4; i++) {
            if (i == i1) continue;
            if (i2 < 0 || pe[i] > pe[i2]) i2 = i;
        }
        tok_e[s * 2 + 0] = base + i1;
        tok_e[s * 2 + 1] = base + i2;
        tok_w[s * 2 + 0] = pe[i1];
        tok_w[s * 2 + 1] = pe[i2];
    }
}

// ---------------------------------------------------------------------------
// Single-block routing build: histogram + scan + scatter in LDS.
// ---------------------------------------------------------------------------
__global__ __launch_bounds__(256) void route_build(const int* __restrict__ tok_e,
                                                   const float* __restrict__ tok_w,
                                                   int* __restrict__ counts_g,
                                                   int* __restrict__ bases_g,
                                                   int* __restrict__ list,
                                                   float* __restrict__ wlist) {
    __shared__ int cnt[E_], bas[E_], cur[E_];
    const int tid = threadIdx.x;
    if (tid < E_) cnt[tid] = 0;
    __syncthreads();
    for (int i = tid; i < 2 * S_; i += 256) atomicAdd(&cnt[tok_e[i]], 1);
    __syncthreads();
    if (tid == 0) {
        int acc = 0;
        for (int e = 0; e < E_; e++) { bas[e] = acc; cur[e] = acc; acc += cnt[e]; }
    }
    __syncthreads();
    if (tid < E_) { counts_g[tid] = cnt[tid]; bases_g[tid] = bas[tid]; }
    for (int i = tid; i < 2 * S_; i += 256) {
        int e = tok_e[i];
        int p = atomicAdd(&cur[e], 1);
        list[p] = i >> 1;
        wlist[p] = tok_w[i];
    }
}

// ---------------------------------------------------------------------------
extern "C" void kernel_launch(void* const* d_in, const int* in_sizes, int n_in,
                              void* d_out, int out_size, void* d_ws, size_t ws_size,
                              hipStream_t stream) {
    const float* src  = (const float*)d_in[0];
    const float* Wq   = (const float*)d_in[1];
    const float* Wk_c = (const float*)d_in[2];
    const float* Wv_c = (const float*)d_in[3];
    const float* Wk   = (const float*)d_in[4];
    const float* Wv   = (const float*)d_in[5];
    const float* Wo   = (const float*)d_in[6];
    const float* Wsin = (const float*)d_in[7];
    const float* Wsout= (const float*)d_in[8];
    const float* W1   = (const float*)d_in[9];
    const float* W2   = (const float*)d_in[10];
    const float* Wg   = (const float*)d_in[11];
    const float* We   = (const float*)d_in[12];
    const float* gb   = (const float*)d_in[13];
    const float* eb   = (const float*)d_in[14];
    const float* n1w  = (const float*)d_in[15];
    const float* n2w  = (const float*)d_in[16];
    float* out = (float*)d_out;

    const size_t MB = 1u << 20;
    char* w8 = (char*)d_ws;
    // Layout (MiB offsets). Lifetimes:
    u16*  qkv   = (u16*)(w8);              // 0..24; dead after attn
    u16*  vtg   = (u16*)(w8 + 24 * MB);    // 24..32; dead after attn
    float* oproj0 = (float*)(w8);          // 0..16 (after attn; dead after rmsnorm1)
    float* oproj1 = (float*)(w8 + 16 * MB);// 16..32 (same)
    u16*  w2t   = (u16*)(w8);              // 0..32 (after rmsnorm1)
    u16*  WkcB  = (u16*)(w8 + 24 * MB);    // early temps (dead before vt_conv)
    u16*  WvcB  = (u16*)(w8 + 24 * MB + 512 * 1024);
    u16*  WkTs  = (u16*)(w8 + 25 * MB);
    u16*  WvTs  = (u16*)(w8 + 25 * MB + 512 * 1024);
    u16*  sab   = (u16*)(w8 + 32 * MB);    // 32..40; dead after Wo gemm
    float* tokw = (float*)(w8 + 32 * MB);  // gating arrays overlay dead sab
    float* wlist = tokw + 2 * S_;
    int* toke   = (int*)(wlist + 2 * S_);
    int* list   = toke + 2 * S_;
    int* counts = list + 2 * S_;
    int* bases  = counts + E_;
    float* x1   = (float*)(w8 + 40 * MB);  // 40..56
    float* ffn0 = (float*)(w8 + 56 * MB);  // 56..72
    u16*  x1b   = (u16*)(w8 + 72 * MB);    // 72..80 (dead after FFN-in gemm)
    u16*  hbuf  = (u16*)(w8 + 80 * MB);    // 80..96 (shared-FFN h)
    u16*  srcb  = (u16*)(w8 + 96 * MB);    // 96..104 (early; dead after QKV gemm)
    float2* rtab= (float2*)(w8 + 104 * MB);// 104..104.5 (dead after rope_apply)
    u16*  hbuf2 = (u16*)(w8 + 96 * MB);    // 96..112 (routed h; after srcb/rtab dead)
    u16*  WqkvT = (u16*)(w8 + 112 * MB);   // 112..118 (early)
    u16*  WsoutT= (u16*)(w8 + 112 * MB);   // 112..116 (after WqkvT dead)
    u16*  WoT   = (u16*)(w8 + 118 * MB);   // 118..120
    u16*  WsinT = (u16*)(w8 + 120 * MB);   // 120..128 (dead after FFN-in)
    u16*  W1T   = (u16*)(w8 + 128 * MB);   // 128..136 (dead after FFN-in)
    float* ffn1 = (float*)(w8 + 120 * MB); // 120..136 (overlays WsinT/W1T, late)

    dim3 blk(256);

    // --- build fused QKV weight (3072 x 1024 bf16, Bt layout) ---
    conv_t<<<dim3(32, 32), blk, 0, stream>>>(Wq, WqkvT, 1024, 1024, 0, 0, 0);
    convert_bf16<<<dim3(D_ * DC_ / 4 / 256), blk, 0, stream>>>(Wk_c, WkcB, D_ * DC_ / 4);
    convert_bf16<<<dim3(D_ * DC_ / 4 / 256), blk, 0, stream>>>(Wv_c, WvcB, D_ * DC_ / 4);
    conv_t<<<dim3(32, 8), blk, 0, stream>>>(Wk, WkTs, 256, 1024, 0, 0, 0);
    conv_t<<<dim3(32, 8), blk, 0, stream>>>(Wv, WvTs, 256, 1024, 0, 0, 0);
    gemm_bf16<2><<<dim3(8, 8), blk, 0, stream>>>(WkcB, WkTs, WqkvT + 1024 * 1024, 1024, 256, 1024, nullptr);
    gemm_bf16<2><<<dim3(8, 8), blk, 0, stream>>>(WvcB, WvTs, WqkvT + 2048 * 1024, 1024, 256, 1024, nullptr);

    convert_bf16<<<dim3(S_ * D_ / 4 / 256), blk, 0, stream>>>(src, srcb, S_ * D_ / 4);

    // Fused QKV projection: (S,1024) @ (1024,3072) -> qkv (S,3072)
    gemm_bf16<1><<<dim3(24, 32), blk, 0, stream>>>(srcb, WqkvT, qkv, QKVW_, 1024, QKVW_, nullptr);

    // other weight conversions (WqkvT dead; WsoutT overlays it)
    conv_t<<<dim3(32, 32), blk, 0, stream>>>(Wo, WoT, 1024, 1024, 0, 0, 0);
    conv_t<<<dim3(128, 32), blk, 0, stream>>>(Wsin, WsinT, 1024, 4096, 0, 0, 1);
    conv_t<<<dim3(32, 64), blk, 0, stream>>>(Wsout, WsoutT, 2048, 1024, 0, 0, 0);
    conv_t<<<dim3(128, 32), blk, 0, stream>>>(W1, W1T, 1024, 4096, 0, 0, 1);

    // RoPE (table + vectorized apply)
    rope_table<<<dim3(T_ * 32 / 256), blk, 0, stream>>>(rtab);
    rope_apply<<<dim3(S_ * 2048 / 8 / 256), blk, 0, stream>>>(qkv, rtab);

    vt_conv<<<dim3(T_ / 32, 2, B_ * H_), blk, 0, stream>>>(qkv, vtg);
    attn_kernel<<<dim3(T_ / 128, B_ * H_), dim3(512), 0, stream>>>(qkv, vtg, sab);

    // Wo projection, split-K=2 plain stores into two buffers
    gemm_bf16<5><<<dim3(8, 32, 2), blk, 0, stream>>>(sab, WoT, oproj0, 1024, 1024, 1024, oproj1);
    rmsnorm_res<1><<<dim3(S_), blk, 0, stream>>>(src, oproj0, oproj1, n1w, x1, x1b);

    // Merged FFN-in (shared + routed W1) with fused swiglu -> hbuf, hbuf2
    gemm_bf16<3><<<dim3(64, 32), blk, 0, stream>>>(x1b, WsinT, hbuf, 8192, 1024, 2048, nullptr);

    // Shared FFN-out, split-K=2 plain stores -> ffn0, ffn1
    gemm_bf16<5><<<dim3(8, 32, 2), blk, 0, stream>>>(hbuf, WsoutT, ffn0, 1024, 2048, 1024, ffn1);

    // Gating + routing lists
    gate_kernel<<<dim3(S_ / 4), blk, 0, stream>>>(x1, Wg, We, gb, eb, toke, tokw);
    route_build<<<dim3(1), blk, 0, stream>>>(toke, tokw, counts, bases, list, wlist);

    // Routed experts: W2 transpose, gathered GEMM atomicAdd onto ffn0
    conv_t<<<dim3(32, 64, 8), blk, 0, stream>>>(W2, w2t, 2048, 1024,
                                                (long)HID_ * D_, (long)D_ * HID_, 0);
    routed_gemm<<<dim3(8, E_ * 32), blk, 0, stream>>>(hbuf2, w2t, list, wlist,
                                                      bases, counts, ffn0);

    rmsnorm_res<0><<<dim3(S_), blk, 0, stream>>>(x1, ffn0, ffn1, n2w, out, (u16*)nullptr);
}

// Round 4
// 631.671 us; speedup vs baseline: 1.2052x; 1.0630x over previous
//
#include <hip/hip_runtime.h>
#include <math.h>

#define D_    1024
#define H_    16
#define DH_   64
#define DC_   256
#define HID_  2048
#define E_    8
#define B_    2
#define T_    2048
#define S_    4096
#define EPS_  1e-6f
#define QKVW_ 3072   // fused qkv row width

typedef unsigned short u16;
typedef short bf16x8 __attribute__((ext_vector_type(8)));
typedef float f32x4 __attribute__((ext_vector_type(4)));

__device__ __forceinline__ float b2f(u16 u) {
    return __uint_as_float(((unsigned int)u) << 16);
}
__device__ __forceinline__ u16 f2b(float f) {
    unsigned int u = __float_as_uint(f);
    u += 0x7FFF + ((u >> 16) & 1);
    return (u16)(u >> 16);
}
__device__ __forceinline__ void g2l16(const u16* g, u16* l) {
    __builtin_amdgcn_global_load_lds(
        (const __attribute__((address_space(1))) void*)g,
        (__attribute__((address_space(3))) void*)l, 16, 0, 0);
}

// ---------------------------------------------------------------------------
// Transpose + fp32->bf16: in (K,N) fp32 -> out (N,K) bf16.
// perm=1: swiglu column interleave for fused epilogue.
// ---------------------------------------------------------------------------
__global__ __launch_bounds__(256) void conv_t(const float* __restrict__ in,
                                              u16* __restrict__ out,
                                              int K, int N,
                                              long inZ, long outZ, int perm) {
    in  += (long)blockIdx.z * inZ;
    out += (long)blockIdx.z * outZ;
    __shared__ float t[32][33];
    const int n0 = blockIdx.x * 32, k0 = blockIdx.y * 32;
    int src_n0 = n0;
    if (perm) {
        int t64 = n0 >> 6;
        src_n0 = ((n0 & 63) == 0) ? t64 * 32 : (N / 2 + t64 * 32);
    }
    const int tx = threadIdx.x & 31, ty = threadIdx.x >> 5;
#pragma unroll
    for (int i = 0; i < 4; i++)
        t[ty + 8 * i][tx] = in[(long)(k0 + ty + 8 * i) * N + src_n0 + tx];
    __syncthreads();
#pragma unroll
    for (int i = 0; i < 4; i++)
        out[(long)(n0 + ty + 8 * i) * K + k0 + tx] = f2b(t[tx][ty + 8 * i]);
}

// bf16 transpose V rows of fused qkv (stride QKVW_) per-head -> Vt [bh][64][T]
__global__ __launch_bounds__(256) void vt_conv(const u16* __restrict__ qkv,
                                               u16* __restrict__ vt) {
    __shared__ u16 t[32][34];
    const int bh = blockIdx.z;
    const int b = bh >> 4, h = bh & 15;
    const int t0 = blockIdx.x * 32, d0 = blockIdx.y * 32;
    const int tx = threadIdx.x & 31, ty = threadIdx.x >> 5;
#pragma unroll
    for (int i = 0; i < 4; i++)
        t[ty + 8 * i][tx] =
            qkv[((long)b * T_ + t0 + ty + 8 * i) * QKVW_ + 2048 + h * 64 + d0 + tx];
    __syncthreads();
#pragma unroll
    for (int i = 0; i < 4; i++)
        vt[((long)bh * 64 + d0 + ty + 8 * i) * T_ + t0 + tx] = t[tx][ty + 8 * i];
}

// Elementwise fp32 -> bf16
__global__ __launch_bounds__(256) void convert_bf16(const float* __restrict__ in,
                                                    u16* __restrict__ out, int n4) {
    int i = blockIdx.x * 256 + threadIdx.x;
    if (i >= n4) return;
    float4 f = ((const float4*)in)[i];
    ushort4 o;
    o.x = f2b(f.x); o.y = f2b(f.y); o.z = f2b(f.z); o.w = f2b(f.w);
    ((ushort4*)out)[i] = o;
}

// ---------------------------------------------------------------------------
// bf16 MFMA GEMM: C(M,N) = A(M,K) @ Bt(N,K)^T. 128x128, BK=32, 4 waves.
// OUTMODE 1: bf16 store | 2: bf16 transposed store (ldo=M)
// OUTMODE 5: split-K (gridDim.z=2), fp32 plain store; z=0 -> Cp, z=1 -> Cp2
// (large-N OUTMODE 1/3 shapes now use gemm256 below)
// ---------------------------------------------------------------------------
template<int OUTMODE>
__global__ __launch_bounds__(256) void gemm_bf16(const u16* __restrict__ A,
                                                 const u16* __restrict__ Bt,
                                                 void* __restrict__ Cp,
                                                 int N, int K, int ldo,
                                                 void* __restrict__ Cp2) {
    __shared__ u16 As[128 * 32];
    __shared__ u16 Bs[128 * 32];
    const int tid  = threadIdx.x;
    const int lane = tid & 63;
    const int wv   = tid >> 6;
    const int wm   = wv >> 1, wn = wv & 1;
    const long row0 = (long)blockIdx.y * 128;
    const long col0 = (long)blockIdx.x * 128;
    const int Klocal = K / gridDim.z;
    const long koff  = (long)blockIdx.z * Klocal;

    f32x4 acc[4][4];
#pragma unroll
    for (int i = 0; i < 4; i++)
#pragma unroll
        for (int j = 0; j < 4; j++) acc[i][j] = (f32x4){0.f, 0.f, 0.f, 0.f};

    const int sr = tid >> 2;
    const int sc = (tid & 3) << 3;
    const u16* Ag  = A  + (row0 + sr) * (long)K + koff + sc;
    const u16* Ag2 = Ag + 64 * (long)K;
    const u16* Bg  = Bt + (col0 + sr) * (long)K + koff + sc;
    const u16* Bg2 = Bg + 64 * (long)K;
    u16* lA  = As + tid * 8;
    u16* lA2 = As + 2048 + tid * 8;
    u16* lB  = Bs + tid * 8;
    u16* lB2 = Bs + 2048 + tid * 8;

    const int fl = lane & 15;
    const int fk = (lane >> 4) << 3;
    const u16* ArA = As + (wm * 64 + fl) * 32 + fk;
    const u16* BrB = Bs + (wn * 64 + fl) * 32 + fk;

    for (int k0 = 0; k0 < Klocal; k0 += 32) {
        __syncthreads();
        g2l16(Ag + k0, lA);
        g2l16(Ag2 + k0, lA2);
        g2l16(Bg + k0, lB);
        g2l16(Bg2 + k0, lB2);
        __syncthreads();
        bf16x8 af[4], bfr[4];
#pragma unroll
        for (int mi = 0; mi < 4; mi++) af[mi]  = *(const bf16x8*)(ArA + mi * 512);
#pragma unroll
        for (int ni = 0; ni < 4; ni++) bfr[ni] = *(const bf16x8*)(BrB + ni * 512);
#pragma unroll
        for (int mi = 0; mi < 4; mi++)
#pragma unroll
            for (int ni = 0; ni < 4; ni++)
                acc[mi][ni] = __builtin_amdgcn_mfma_f32_16x16x32_bf16(
                    af[mi], bfr[ni], acc[mi][ni], 0, 0, 0);
    }

    const int cr = (lane >> 4) << 2;
    const int cc = lane & 15;
#pragma unroll
    for (int mi = 0; mi < 4; mi++) {
#pragma unroll
        for (int r = 0; r < 4; r++) {
            long grow = row0 + wm * 64 + mi * 16 + cr + r;
#pragma unroll
            for (int ni = 0; ni < 4; ni++) {
                long gcol = col0 + wn * 64 + ni * 16 + cc;
                float v = acc[mi][ni][r];
                if (OUTMODE == 1)      ((u16*)Cp)[grow * ldo + gcol] = f2b(v);
                else if (OUTMODE == 2) ((u16*)Cp)[gcol * ldo + grow] = f2b(v);
                else {
                    float* basep = (float*)(blockIdx.z ? Cp2 : Cp);
                    basep[grow * ldo + gcol] = v;
                }
            }
        }
    }
}

// ---------------------------------------------------------------------------
// 256x256 bf16 MFMA GEMM, BK=64, 8 waves, T3-minimum pipeline:
//   stage(j+1) ISSUED before tile j's ds_read+MFMA; ONE __syncthreads per
//   K-tile (its implicit vmcnt(0) drain now has a full compute phase of
//   cover). LDS 2x(32+32)KB = 128KB -> 1 block/CU. Conflict-free ds_read via
//   XOR-8 slot swizzle (128B rows; pre-swizzled global source, linear LDS --
//   same pattern as attn Ks, measured 0 conflicts).
// OUTMODE 1: plain bf16 store. OUTMODE 3: swiglu epilogue, dual output
//   (blockIdx.x>=16 -> Cp + S_*HID_), ldo = HID_.
// ---------------------------------------------------------------------------
template<int OUTMODE>
__global__ __launch_bounds__(512) void gemm256(const u16* __restrict__ A,
                                               const u16* __restrict__ Bt,
                                               void* __restrict__ Cp,
                                               int K, int ldo) {
    __shared__ u16 As[2][256 * 64];
    __shared__ u16 Bs[2][256 * 64];
    const int tid  = threadIdx.x;
    const int lane = tid & 63;
    const int w    = tid >> 6;           // 0..7
    const int wr   = w >> 2, wc = w & 3; // 2 x 4 wave grid
    const long row0 = (long)blockIdx.y * 256;
    const long col0 = (long)blockIdx.x * 256;

    f32x4 acc[8][4];
#pragma unroll
    for (int i = 0; i < 8; i++)
#pragma unroll
        for (int j = 0; j < 4; j++) acc[i][j] = (f32x4){0.f, 0.f, 0.f, 0.f};

    // Staging: per round 512thr x 16B = 64 rows x 64k. row = tid>>3,
    // slot = tid&7; source k-group pre-swizzled (slot ^ row&7) so LDS slot g
    // of row r holds global k-group g^(r&7). Rows r, r+64, r+128, r+192
    // share (r&7) -> same swizzle offset.
    const int srow = tid >> 3;                       // 0..63
    const int sgS  = ((tid & 7) ^ (srow & 7)) << 3;  // u16 offset
    const u16* Ag = A  + (row0 + srow) * (long)K + sgS;
    const u16* Bg = Bt + (col0 + srow) * (long)K + sgS;

    const int fl = lane & 15;
    const int fq = lane >> 4;
    const int aoff = (wr * 128 + fl) * 64;   // + mi*1024
    const int boff = (wc * 64 + fl) * 64;    // + ni*1024

#define STAGE256(j, buf) do {                                             \
        const long ko_ = (long)(j) * 64;                                  \
        u16* la_ = As[buf] + tid * 8;                                     \
        u16* lb_ = Bs[buf] + tid * 8;                                     \
        _Pragma("unroll")                                                 \
        for (int rr_ = 0; rr_ < 4; rr_++)                                 \
            g2l16(Ag + (long)rr_ * 64 * K + ko_, la_ + rr_ * 4096);       \
        _Pragma("unroll")                                                 \
        for (int rr_ = 0; rr_ < 4; rr_++)                                 \
            g2l16(Bg + (long)rr_ * 64 * K + ko_, lb_ + rr_ * 4096);       \
    } while (0)

    STAGE256(0, 0);
    __syncthreads();                 // tile 0 landed (implicit vmcnt(0))
    const int NT = K >> 6;
    for (int j = 0; j < NT; j++) {
        const int buf = j & 1;
        if (j + 1 < NT) STAGE256(j + 1, buf ^ 1);   // issue-early (T14/T3)
        const u16* ab = As[buf];
        const u16* bb = Bs[buf];
#pragma unroll
        for (int ks = 0; ks < 2; ks++) {
            const int sw = ((ks * 4 + fq) ^ (fl & 7)) << 3;
            bf16x8 af[8], bfr[4];
#pragma unroll
            for (int mi = 0; mi < 8; mi++)
                af[mi] = *(const bf16x8*)(ab + aoff + mi * 1024 + sw);
#pragma unroll
            for (int ni = 0; ni < 4; ni++)
                bfr[ni] = *(const bf16x8*)(bb + boff + ni * 1024 + sw);
#pragma unroll
            for (int mi = 0; mi < 8; mi++)
#pragma unroll
                for (int ni = 0; ni < 4; ni++)
                    acc[mi][ni] = __builtin_amdgcn_mfma_f32_16x16x32_bf16(
                        af[mi], bfr[ni], acc[mi][ni], 0, 0, 0);
        }
        // Single barrier per K-tile: drains stage(j+1) (issued a full
        // compute phase ago) and orders buf reuse for stage(j+2).
        __syncthreads();
    }

    const int cr = fq << 2;
    const int cc = fl;
#pragma unroll
    for (int mi = 0; mi < 8; mi++) {
#pragma unroll
        for (int r = 0; r < 4; r++) {
            long grow = row0 + wr * 128 + mi * 16 + cr + r;
            if (OUTMODE == 3) {
                u16* outb = (u16*)Cp + (long)(blockIdx.x >> 4) * S_ * HID_;
                u16* hrow = outb + grow * ldo + (blockIdx.x & 15) * 128 + wc * 32;
#pragma unroll
                for (int ni = 0; ni < 2; ni++) {
                    float a = acc[mi][ni][r], b = acc[mi][ni + 2][r];
                    float sig = 1.f / (1.f + __expf(-a));
                    hrow[ni * 16 + cc] = f2b(a * sig * b);
                }
            } else {
#pragma unroll
                for (int ni = 0; ni < 4; ni++) {
                    long gcol = col0 + wc * 64 + ni * 16 + cc;
                    ((u16*)Cp)[grow * ldo + gcol] = f2b(acc[mi][ni][r]);
                }
            }
        }
    }
#undef STAGE256
}

// ---------------------------------------------------------------------------
// Routed-expert bf16 MFMA GEMM (gathered rows, scaled atomicAdd epilogue)
// ---------------------------------------------------------------------------
__global__ __launch_bounds__(256) void routed_gemm(const u16* __restrict__ Hh,
                                                   const u16* __restrict__ W2T,
                                                   const int* __restrict__ list,
                                                   const float* __restrict__ wlist,
                                                   const int* __restrict__ bases,
                                                   const int* __restrict__ counts,
                                                   float* __restrict__ Cout) {
    const int e    = blockIdx.y >> 5;
    const int tile = blockIdx.y & 31;
    const int cnt  = counts[e];
    if (tile * 128 >= cnt) return;
    const int base = bases[e];

    __shared__ u16 As[128 * 32];
    __shared__ u16 Bs[128 * 32];
    __shared__ int   toks[128];
    __shared__ float wrow[128];

    const int tid = threadIdx.x;
    if (tid < 128) {
        int ridx = tile * 128 + tid;
        if (ridx < cnt) { toks[tid] = list[base + ridx]; wrow[tid] = wlist[base + ridx]; }
        else            { toks[tid] = -1;                wrow[tid] = 0.f; }
    }
    __syncthreads();

    const int lane = tid & 63;
    const int wv   = tid >> 6;
    const int wm   = wv >> 1, wn = wv & 1;
    const long col0 = (long)blockIdx.x * 128;

    f32x4 acc[4][4];
#pragma unroll
    for (int i = 0; i < 4; i++)
#pragma unroll
        for (int j = 0; j < 4; j++) acc[i][j] = (f32x4){0.f, 0.f, 0.f, 0.f};

    const int sr = tid >> 2;
    const int sc = (tid & 3) << 3;
    const int t1 = toks[sr], t2 = toks[sr + 64];
    const u16* Ag  = Hh + (long)(t1 < 0 ? 0 : t1) * HID_ + sc;
    const u16* Ag2 = Hh + (long)(t2 < 0 ? 0 : t2) * HID_ + sc;
    const u16* Bg  = W2T + (long)e * D_ * HID_ + (col0 + sr) * (long)HID_ + sc;
    const u16* Bg2 = Bg + 64 * (long)HID_;
    u16* lA  = As + tid * 8;
    u16* lA2 = As + 2048 + tid * 8;
    u16* lB  = Bs + tid * 8;
    u16* lB2 = Bs + 2048 + tid * 8;

    const int fl = lane & 15;
    const int fk = (lane >> 4) << 3;
    const u16* ArA = As + (wm * 64 + fl) * 32 + fk;
    const u16* BrB = Bs + (wn * 64 + fl) * 32 + fk;

    for (int k0 = 0; k0 < HID_; k0 += 32) {
        __syncthreads();
        g2l16(Ag + k0, lA);
        g2l16(Ag2 + k0, lA2);
        g2l16(Bg + k0, lB);
        g2l16(Bg2 + k0, lB2);
        __syncthreads();
        bf16x8 af[4], bfr[4];
#pragma unroll
        for (int mi = 0; mi < 4; mi++) af[mi]  = *(const bf16x8*)(ArA + mi * 512);
#pragma unroll
        for (int ni = 0; ni < 4; ni++) bfr[ni] = *(const bf16x8*)(BrB + ni * 512);
#pragma unroll
        for (int mi = 0; mi < 4; mi++)
#pragma unroll
            for (int ni = 0; ni < 4; ni++)
                acc[mi][ni] = __builtin_amdgcn_mfma_f32_16x16x32_bf16(
                    af[mi], bfr[ni], acc[mi][ni], 0, 0, 0);
    }

    const int cr = (lane >> 4) << 2;
    const int cc = lane & 15;
#pragma unroll
    for (int mi = 0; mi < 4; mi++) {
#pragma unroll
        for (int r = 0; r < 4; r++) {
            int rr = wm * 64 + mi * 16 + cr + r;
            int tk = toks[rr];
            if (tk < 0) continue;
            float wvw = wrow[rr];
            float* crow = Cout + (long)tk * D_ + col0 + wn * 64;
#pragma unroll
            for (int ni = 0; ni < 4; ni++)
                atomicAdd(crow + ni * 16 + cc, acc[mi][ni][r] * wvw);
        }
    }
}

// ---------------------------------------------------------------------------
// RoPE: sincos table (T_ x 32) then vectorized apply on q,k cols of qkv.
// ---------------------------------------------------------------------------
__global__ __launch_bounds__(256) void rope_table(float2* __restrict__ tab) {
    int idx = blockIdx.x * 256 + threadIdx.x;     // 65536
    int t = idx >> 5, i = idx & 31;
    float ang = (float)t * powf(10000.f, -(float)i / 32.f);
    float sn, cs;
    sincosf(ang, &sn, &cs);
    tab[idx] = make_float2(sn, cs);
}

__global__ __launch_bounds__(256) void rope_apply(u16* __restrict__ qkv,
                                                  const float2* __restrict__ tab) {
    long p = (long)blockIdx.x * 256 + threadIdx.x;   // S_*2048/8 groups
    int s  = (int)(p >> 8);
    int c8 = (int)(p & 255) << 3;
    int t  = s & (T_ - 1);
    const float2* tp = tab + t * 32 + ((c8 & 63) >> 1);
    u16* px = qkv + (long)s * QKVW_ + c8;
    bf16x8 v = *(const bf16x8*)px;
    bf16x8 o;
#pragma unroll
    for (int j = 0; j < 4; j++) {
        float x1 = b2f((u16)v[2 * j]), x2 = b2f((u16)v[2 * j + 1]);
        float2 sc = tp[j];
        o[2 * j]     = (short)f2b(x1 * sc.y - x2 * sc.x);
        o[2 * j + 1] = (short)f2b(x1 * sc.x + x2 * sc.y);
    }
    *(bf16x8*)px = o;
}

// ---------------------------------------------------------------------------
// MFMA flash attention, 128-key x 128-query tiles. grid (T/128, B*H),
// 512 thr = 8 waves x 16 q-rows. (v4: reg-staged T14 split, XCD swizzle,
// setprio, defer-max; plain launch bounds.)
// ---------------------------------------------------------------------------
__global__ __launch_bounds__(512) void attn_kernel(const u16* __restrict__ qkv,
                                                   const u16* __restrict__ vtg,
                                                   u16* __restrict__ sab) {
    __shared__ u16 Ks[128 * 64];
    __shared__ u16 Vs[64 * 128];
    __shared__ u16 Ps[8][16 * 128];
    const int tid  = threadIdx.x;
    const int lane = tid & 63;
    const int w    = tid >> 6;          // 0..7
    const int flat = blockIdx.x + (blockIdx.y << 4);
    const int virt = ((flat & 7) << 6) | (flat >> 3);
    const int qt = virt & 15;
    const int bh = virt >> 4;
    const int b  = bh >> 4, h = bh & 15;
    const long tok0 = (long)b * T_ + qt * 128;
    const int fl = lane & 15;
    const int fq = lane >> 4;

    bf16x8 qf0, qf1;
    {
        const u16* qp = qkv + (tok0 + w * 16 + fl) * QKVW_ + h * 64 + fq * 8;
        qf0 = *(const bf16x8*)qp;
        qf1 = *(const bf16x8*)(qp + 32);
    }

    const u16* kb0 = qkv + ((long)b * T_) * QKVW_ + 1024 + h * 64;
    const u16* vb0 = vtg + ((long)bh * 64) * T_;

    const int kr0 = tid >> 3,         kgg = tid & 7;
    const int kr1 = (tid + 512) >> 3;
    const int vr0 = tid >> 4,         vgg = tid & 15;
    const int vr1 = (tid + 512) >> 4;
    const u16* kp0 = kb0 + (long)kr0 * QKVW_ + ((kgg ^ (kr0 & 7)) << 3);
    const u16* kp1 = kb0 + (long)kr1 * QKVW_ + ((kgg ^ (kr1 & 7)) << 3);
    const u16* vp0 = vb0 + (long)vr0 * T_ + ((vgg ^ (vr0 & 15)) << 3);
    const u16* vp1 = vb0 + (long)vr1 * T_ + ((vgg ^ (vr1 & 15)) << 3);
    u16* kl0 = Ks + tid * 8;
    u16* kl1 = Ks + (tid + 512) * 8;
    u16* vl0 = Vs + tid * 8;
    u16* vl1 = Vs + (tid + 512) * 8;

    bf16x8 kreg0, kreg1, vreg0, vreg1;
    auto stage_load = [&](int kt) {
        const long ko = (long)kt * 128 * QKVW_;
        const int  vo = kt * 128;
        kreg0 = *(const bf16x8*)(kp0 + ko);
        kreg1 = *(const bf16x8*)(kp1 + ko);
        vreg0 = *(const bf16x8*)(vp0 + vo);
        vreg1 = *(const bf16x8*)(vp1 + vo);
    };
    auto stage_write = [&]() {
        *(bf16x8*)kl0 = kreg0;
        *(bf16x8*)kl1 = kreg1;
        *(bf16x8*)vl0 = vreg0;
        *(bf16x8*)vl1 = vreg1;
    };

    float m_[4], l_[4];
    f32x4 oacc[4];
#pragma unroll
    for (int i = 0; i < 4; i++) {
        m_[i] = -1e30f; l_[i] = 0.f;
        oacc[i] = (f32x4){0.f, 0.f, 0.f, 0.f};
    }

    stage_load(0);
    stage_write();
    __syncthreads();

    for (int kt = 0; kt < T_ / 128; kt++) {
        const bool pf = (kt + 1 < T_ / 128);
        if (pf) stage_load(kt + 1);

        f32x4 sacc[8];
#pragma unroll
        for (int ni = 0; ni < 8; ni++) sacc[ni] = (f32x4){0.f, 0.f, 0.f, 0.f};
        __builtin_amdgcn_s_setprio(1);
#pragma unroll
        for (int ks = 0; ks < 2; ks++) {
            bf16x8 qq = ks ? qf1 : qf0;
#pragma unroll
            for (int ni = 0; ni < 8; ni++) {
                bf16x8 kf = *(const bf16x8*)(Ks + (ni * 16 + fl) * 64 +
                                             (((ks * 4 + fq) ^ (fl & 7)) << 3));
                sacc[ni] = __builtin_amdgcn_mfma_f32_16x16x32_bf16(qq, kf, sacc[ni], 0, 0, 0);
            }
        }
        __builtin_amdgcn_s_setprio(0);

        float rmax[4];
#pragma unroll
        for (int r = 0; r < 4; r++) {
            float mm = sacc[0][r];
#pragma unroll
            for (int ni = 1; ni < 8; ni++) mm = fmaxf(mm, sacc[ni][r]);
            rmax[r] = mm * 0.125f;
        }
#pragma unroll
        for (int off = 1; off < 16; off <<= 1)
#pragma unroll
            for (int r = 0; r < 4; r++) rmax[r] = fmaxf(rmax[r], __shfl_xor(rmax[r], off));

        bool grow = false;
        float nm[4];
#pragma unroll
        for (int r = 0; r < 4; r++) {
            nm[r] = fmaxf(m_[r], rmax[r]);
            grow = grow || (rmax[r] > m_[r] + 8.f);
        }
        if (__any(grow)) {
#pragma unroll
            for (int r = 0; r < 4; r++) {
                float a = __expf(m_[r] - nm[r]);
                m_[r] = nm[r];
                l_[r] *= a;
#pragma unroll
                for (int ni = 0; ni < 4; ni++) oacc[ni][r] *= a;
            }
        }

        float psum[4];
#pragma unroll
        for (int r = 0; r < 4; r++) psum[r] = 0.f;
        u16* pst = Ps[w];
#pragma unroll
        for (int ni = 0; ni < 8; ni++) {
            int colg = ni * 2 + (fl >> 3);
            int cl   = fl & 7;
#pragma unroll
            for (int r = 0; r < 4; r++) {
                int row = fq * 4 + r;
                float p = __expf(sacc[ni][r] * 0.125f - m_[r]);
                psum[r] += p;
                pst[row * 128 + ((colg ^ (row & 15)) << 3) + cl] = f2b(p);
            }
        }
#pragma unroll
        for (int off = 1; off < 16; off <<= 1)
#pragma unroll
            for (int r = 0; r < 4; r++) psum[r] += __shfl_xor(psum[r], off);
#pragma unroll
        for (int r = 0; r < 4; r++) l_[r] += psum[r];

        __builtin_amdgcn_s_setprio(1);
#pragma unroll
        for (int ks = 0; ks < 4; ks++) {
            bf16x8 pfr = *(const bf16x8*)(pst + fl * 128 +
                                          (((ks * 4 + fq) ^ fl) << 3));
#pragma unroll
            for (int ni = 0; ni < 4; ni++) {
                bf16x8 vf = *(const bf16x8*)(Vs + (ni * 16 + fl) * 128 +
                                             (((ks * 4 + fq) ^ fl) << 3));
                oacc[ni] = __builtin_amdgcn_mfma_f32_16x16x32_bf16(pfr, vf, oacc[ni], 0, 0, 0);
            }
        }
        __builtin_amdgcn_s_setprio(0);

        __syncthreads();
        if (pf) {
            stage_write();
            __syncthreads();
        }
    }

#pragma unroll
    for (int r = 0; r < 4; r++) {
        float inv = 1.f / l_[r];
        u16* op = sab + (tok0 + w * 16 + fq * 4 + r) * D_ + h * 64 + fl;
#pragma unroll
        for (int ni = 0; ni < 4; ni++) op[ni * 16] = f2b(oacc[ni][r] * inv);
    }
}

// ---------------------------------------------------------------------------
// Residual add (3 inputs) + RMSNorm. BF=1 additionally writes bf16 copy.
// ---------------------------------------------------------------------------
template<int BF>
__global__ __launch_bounds__(256) void rmsnorm_res(const float* __restrict__ a,
                                                   const float* __restrict__ b,
                                                   const float* __restrict__ b2,
                                                   const float* __restrict__ w,
                                                   float* __restrict__ outf,
                                                   u16* __restrict__ outb) {
    const int s = blockIdx.x;
    const float* ar = a + (long)s * D_;
    const float* br = b + (long)s * D_;
    const float* cr2 = b2 + (long)s * D_;
    float y[4];
    float ss = 0.f;
#pragma unroll
    for (int kx = 0; kx < 4; kx++) {
        int j = threadIdx.x + kx * 256;
        y[kx] = ar[j] + br[j] + cr2[j];
        ss += y[kx] * y[kx];
    }
    __shared__ float red[4];
#pragma unroll
    for (int off = 32; off > 0; off >>= 1) ss += __shfl_down(ss, off);
    int lane = threadIdx.x & 63, wv = threadIdx.x >> 6;
    if (lane == 0) red[wv] = ss;
    __syncthreads();
    float tot = red[0] + red[1] + red[2] + red[3];
    float scl = rsqrtf(tot / (float)D_ + EPS_);
    float* orow = outf + (long)s * D_;
#pragma unroll
    for (int kx = 0; kx < 4; kx++) {
        int j = threadIdx.x + kx * 256;
        float v = y[kx] * scl * w[j];
        orow[j] = v;
        if (BF) outb[(long)s * D_ + j] = f2b(v);
    }
}

// ---------------------------------------------------------------------------
// Gating (fp32): one wave per token. Writes per-token top-2 (expert, weight).
// ---------------------------------------------------------------------------
__global__ __launch_bounds__(256) void gate_kernel(const float* __restrict__ x,
                                                   const float* __restrict__ Wg,
                                                   const float* __restrict__ We,
                                                   const float* __restrict__ gb,
                                                   const float* __restrict__ eb,
                                                   int* __restrict__ tok_e,
                                                   float* __restrict__ tok_w) {
    const int wave = threadIdx.x >> 6;
    const int lane = threadIdx.x & 63;
    const int s = blockIdx.x * 4 + wave;
    const float* xr = x + (long)s * D_;
    float g0 = 0.f, g1 = 0.f;
    float ee[8];
#pragma unroll
    for (int e = 0; e < 8; e++) ee[e] = 0.f;
    for (int j = lane; j < D_; j += 64) {
        float xv = xr[j];
        g0 += xv * Wg[j * 2 + 0];
        g1 += xv * Wg[j * 2 + 1];
#pragma unroll
        for (int e = 0; e < 8; e++) ee[e] += xv * We[j * 8 + e];
    }
#pragma unroll
    for (int off = 32; off > 0; off >>= 1) {
        g0 += __shfl_down(g0, off);
        g1 += __shfl_down(g1, off);
#pragma unroll
        for (int e = 0; e < 8; e++) ee[e] += __shfl_down(ee[e], off);
    }
    if (lane == 0) {
        g0 += gb[0];
        g1 += gb[1];
        int gidx = (g1 > g0) ? 1 : 0;
        float gm = fmaxf(g0, g1);
        float p0 = expf(g0 - gm), p1 = expf(g1 - gm);
        float gprob = (gidx ? p1 : p0) / (p0 + p1);
        int base = gidx * 4;
        float pe[4];
        float em = -1e30f;
#pragma unroll
        for (int i = 0; i < 4; i++) {
            pe[i] = ee[base + i] + eb[base + i];
            em = fmaxf(em, pe[i]);
        }
        float sum = 0.f;
#pragma unroll
        for (int i = 0; i < 4; i++) { pe[i] = expf(pe[i] - em); sum += pe[i]; }
        float inv = gprob / sum;
#pragma unroll
        for (int i = 0; i < 4; i++) pe[i] *= inv;
        int i1 = 0;
        for (int i = 1; i < 4; i++) if (pe[i] > pe[i1]) i1 = i;
        int i2 = -1;
        for (int i = 0; i < 4; i++) {
            if (i == i1) continue;
            if (i2 < 0 || pe[i] > pe[i2]) i2 = i;
        }
        tok_e[s * 2 + 0] = base + i1;
        tok_e[s * 2 + 1] = base + i2;
        tok_w[s * 2 + 0] = pe[i1];
        tok_w[s * 2 + 1] = pe[i2];
    }
}

// ---------------------------------------------------------------------------
// Single-block routing build: histogram + scan + scatter in LDS.
// ---------------------------------------------------------------------------
__global__ __launch_bounds__(256) void route_build(const int* __restrict__ tok_e,
                                                   const float* __restrict__ tok_w,
                                                   int* __restrict__ counts_g,
                                                   int* __restrict__ bases_g,
                                                   int* __restrict__ list,
                                                   float* __restrict__ wlist) {
    __shared__ int cnt[E_], bas[E_], cur[E_];
    const int tid = threadIdx.x;
    if (tid < E_) cnt[tid] = 0;
    __syncthreads();
    for (int i = tid; i < 2 * S_; i += 256) atomicAdd(&cnt[tok_e[i]], 1);
    __syncthreads();
    if (tid == 0) {
        int acc = 0;
        for (int e = 0; e < E_; e++) { bas[e] = acc; cur[e] = acc; acc += cnt[e]; }
    }
    __syncthreads();
    if (tid < E_) { counts_g[tid] = cnt[tid]; bases_g[tid] = bas[tid]; }
    for (int i = tid; i < 2 * S_; i += 256) {
        int e = tok_e[i];
        int p = atomicAdd(&cur[e], 1);
        list[p] = i >> 1;
        wlist[p] = tok_w[i];
    }
}

// ---------------------------------------------------------------------------
extern "C" void kernel_launch(void* const* d_in, const int* in_sizes, int n_in,
                              void* d_out, int out_size, void* d_ws, size_t ws_size,
                              hipStream_t stream) {
    const float* src  = (const float*)d_in[0];
    const float* Wq   = (const float*)d_in[1];
    const float* Wk_c = (const float*)d_in[2];
    const float* Wv_c = (const float*)d_in[3];
    const float* Wk   = (const float*)d_in[4];
    const float* Wv   = (const float*)d_in[5];
    const float* Wo   = (const float*)d_in[6];
    const float* Wsin = (const float*)d_in[7];
    const float* Wsout= (const float*)d_in[8];
    const float* W1   = (const float*)d_in[9];
    const float* W2   = (const float*)d_in[10];
    const float* Wg   = (const float*)d_in[11];
    const float* We   = (const float*)d_in[12];
    const float* gb   = (const float*)d_in[13];
    const float* eb   = (const float*)d_in[14];
    const float* n1w  = (const float*)d_in[15];
    const float* n2w  = (const float*)d_in[16];
    float* out = (float*)d_out;

    const size_t MB = 1u << 20;
    char* w8 = (char*)d_ws;
    // Layout (MiB offsets). Lifetimes:
    u16*  qkv   = (u16*)(w8);              // 0..24; dead after attn
    u16*  vtg   = (u16*)(w8 + 24 * MB);    // 24..32; dead after attn
    float* oproj0 = (float*)(w8);          // 0..16 (after attn; dead after rmsnorm1)
    float* oproj1 = (float*)(w8 + 16 * MB);// 16..32 (same)
    u16*  w2t   = (u16*)(w8);              // 0..32 (after rmsnorm1)
    u16*  WkcB  = (u16*)(w8 + 24 * MB);    // early temps (dead before vt_conv)
    u16*  WvcB  = (u16*)(w8 + 24 * MB + 512 * 1024);
    u16*  WkTs  = (u16*)(w8 + 25 * MB);
    u16*  WvTs  = (u16*)(w8 + 25 * MB + 512 * 1024);
    u16*  sab   = (u16*)(w8 + 32 * MB);    // 32..40; dead after Wo gemm
    float* tokw = (float*)(w8 + 32 * MB);  // gating arrays overlay dead sab
    float* wlist = tokw + 2 * S_;
    int* toke   = (int*)(wlist + 2 * S_);
    int* list   = toke + 2 * S_;
    int* counts = list + 2 * S_;
    int* bases  = counts + E_;
    float* x1   = (float*)(w8 + 40 * MB);  // 40..56
    float* ffn0 = (float*)(w8 + 56 * MB);  // 56..72
    u16*  x1b   = (u16*)(w8 + 72 * MB);    // 72..80 (dead after FFN-in gemm)
    u16*  hbuf  = (u16*)(w8 + 80 * MB);    // 80..96 (shared-FFN h)
    u16*  srcb  = (u16*)(w8 + 96 * MB);    // 96..104 (early; dead after QKV gemm)
    float2* rtab= (float2*)(w8 + 104 * MB);// 104..104.5 (dead after rope_apply)
    u16*  hbuf2 = (u16*)(w8 + 96 * MB);    // 96..112 (routed h; after srcb/rtab dead)
    u16*  WqkvT = (u16*)(w8 + 112 * MB);   // 112..118 (early)
    u16*  WsoutT= (u16*)(w8 + 112 * MB);   // 112..116 (after WqkvT dead)
    u16*  WoT   = (u16*)(w8 + 118 * MB);   // 118..120
    u16*  WsinT = (u16*)(w8 + 120 * MB);   // 120..128 (dead after FFN-in)
    u16*  W1T   = (u16*)(w8 + 128 * MB);   // 128..136 (dead after FFN-in)
    float* ffn1 = (float*)(w8 + 120 * MB); // 120..136 (overlays WsinT/W1T, late)

    dim3 blk(256);

    // --- build fused QKV weight (3072 x 1024 bf16, Bt layout) ---
    conv_t<<<dim3(32, 32), blk, 0, stream>>>(Wq, WqkvT, 1024, 1024, 0, 0, 0);
    convert_bf16<<<dim3(D_ * DC_ / 4 / 256), blk, 0, stream>>>(Wk_c, WkcB, D_ * DC_ / 4);
    convert_bf16<<<dim3(D_ * DC_ / 4 / 256), blk, 0, stream>>>(Wv_c, WvcB, D_ * DC_ / 4);
    conv_t<<<dim3(32, 8), blk, 0, stream>>>(Wk, WkTs, 256, 1024, 0, 0, 0);
    conv_t<<<dim3(32, 8), blk, 0, stream>>>(Wv, WvTs, 256, 1024, 0, 0, 0);
    gemm_bf16<2><<<dim3(8, 8), blk, 0, stream>>>(WkcB, WkTs, WqkvT + 1024 * 1024, 1024, 256, 1024, nullptr);
    gemm_bf16<2><<<dim3(8, 8), blk, 0, stream>>>(WvcB, WvTs, WqkvT + 2048 * 1024, 1024, 256, 1024, nullptr);

    convert_bf16<<<dim3(S_ * D_ / 4 / 256), blk, 0, stream>>>(src, srcb, S_ * D_ / 4);

    // Fused QKV projection: (S,1024) @ (1024,3072) -> qkv (S,3072)  [256² pipeline]
    gemm256<1><<<dim3(QKVW_ / 256, S_ / 256), dim3(512), 0, stream>>>(srcb, WqkvT, qkv, 1024, QKVW_);

    // other weight conversions (WqkvT dead; WsoutT overlays it)
    conv_t<<<dim3(32, 32), blk, 0, stream>>>(Wo, WoT, 1024, 1024, 0, 0, 0);
    conv_t<<<dim3(128, 32), blk, 0, stream>>>(Wsin, WsinT, 1024, 4096, 0, 0, 1);
    conv_t<<<dim3(32, 64), blk, 0, stream>>>(Wsout, WsoutT, 2048, 1024, 0, 0, 0);
    conv_t<<<dim3(128, 32), blk, 0, stream>>>(W1, W1T, 1024, 4096, 0, 0, 1);

    // RoPE (table + vectorized apply)
    rope_table<<<dim3(T_ * 32 / 256), blk, 0, stream>>>(rtab);
    rope_apply<<<dim3(S_ * 2048 / 8 / 256), blk, 0, stream>>>(qkv, rtab);

    vt_conv<<<dim3(T_ / 32, 2, B_ * H_), blk, 0, stream>>>(qkv, vtg);
    attn_kernel<<<dim3(T_ / 128, B_ * H_), dim3(512), 0, stream>>>(qkv, vtg, sab);

    // Wo projection, split-K=2 plain stores into two buffers
    gemm_bf16<5><<<dim3(8, 32, 2), blk, 0, stream>>>(sab, WoT, oproj0, 1024, 1024, 1024, oproj1);
    rmsnorm_res<1><<<dim3(S_), blk, 0, stream>>>(src, oproj0, oproj1, n1w, x1, x1b);

    // Merged FFN-in (shared + routed W1) with fused swiglu -> hbuf, hbuf2  [256² pipeline]
    gemm256<3><<<dim3(8192 / 256, S_ / 256), dim3(512), 0, stream>>>(x1b, WsinT, hbuf, 1024, 2048);

    // Shared FFN-out, split-K=2 plain stores -> ffn0, ffn1
    gemm_bf16<5><<<dim3(8, 32, 2), blk, 0, stream>>>(hbuf, WsoutT, ffn0, 1024, 2048, 1024, ffn1);

    // Gating + routing lists
    gate_kernel<<<dim3(S_ / 4), blk, 0, stream>>>(x1, Wg, We, gb, eb, toke, tokw);
    route_build<<<dim3(1), blk, 0, stream>>>(toke, tokw, counts, bases, list, wlist);

    // Routed experts: W2 transpose, gathered GEMM atomicAdd onto ffn0
    conv_t<<<dim3(32, 64, 8), blk, 0, stream>>>(W2, w2t, 2048, 1024,
                                                (long)HID_ * D_, (long)D_ * HID_, 0);
    routed_gemm<<<dim3(8, E_ * 32), blk, 0, stream>>>(hbuf2, w2t, list, wlist,
                                                      bases, counts, ffn0);

    rmsnorm_res<0><<<dim3(S_), blk, 0, stream>>>(x1, ffn0, ffn1, n2w, out, (u16*)nullptr);
}